// Round 3
// baseline (529.459 us; speedup 1.0000x reference)
//
#include <hip/hip_runtime.h>
#include <stdint.h>

#define NPATHS 4096
#define LPATH  8
#define DIM    256
#define HID    256

typedef short  short4v __attribute__((ext_vector_type(4)));
typedef short  short8v __attribute__((ext_vector_type(8)));
typedef float  float4v __attribute__((ext_vector_type(4)));

__device__ __forceinline__ unsigned short f2bf(float f) {
    union { float f; uint32_t u; } v; v.f = f;
    uint32_t u = v.u;
    u += 0x7FFFu + ((u >> 16) & 1u);   // round-to-nearest-even
    return (unsigned short)(u >> 16);
}
__device__ __forceinline__ float bf2f(unsigned short s) {
    return __uint_as_float(((uint32_t)s) << 16);
}
__device__ __forceinline__ float fast_sigmoid(float x) {
    return 1.0f / (1.0f + __expf(-x));
}
__device__ __forceinline__ float fast_tanh(float x) {
    x = fminf(15.0f, fmaxf(-15.0f, x));
    float e = __expf(2.0f * x);
    return (e - 1.0f) / (e + 1.0f);
}

// ---------------------------------------------------------------------------
// K0: pack weights into B-fragment order + bias + zero path_emb/done.
// WfB (shorts): [(g*16+kc)][unit][quad*8+j] -> step wave load is coalesced.
// ---------------------------------------------------------------------------
__global__ void prep_kernel(const float* __restrict__ w_ih, const float* __restrict__ w_hh,
                            const float* __restrict__ b_ih, const float* __restrict__ b_hh,
                            unsigned short* __restrict__ WfB, float* __restrict__ bias,
                            float* __restrict__ path_emb, unsigned int* __restrict__ done) {
    int gid  = blockIdx.x * 256 + threadIdx.x;    // 0..131071
    int base = gid * 4;                           // short index, %4==0
    int j0   = base & 31;                         // quad*8+j
    int unit = (base >> 5) & 255;
    int gkc  = base >> 13;                        // g*16+kc, 0..63
    int g    = gkc >> 4, kc = gkc & 15;
    int row  = g * 256 + unit;
    int k    = kc * 32 + j0;
    const float* src = (k < DIM) ? (w_ih + (size_t)row * DIM + k)
                                 : (w_hh + (size_t)row * HID + (k - DIM));
    float4 v = *(const float4*)src;
    short4v pk = {(short)f2bf(v.x), (short)f2bf(v.y), (short)f2bf(v.z), (short)f2bf(v.w)};
    *(short4v*)(WfB + base) = pk;
    if (gid < 1024) bias[gid] = b_ih[gid] + b_hh[gid];
    if (gid < 256)  path_emb[gid] = 0.0f;
    if (gid == 0)   *done = 0u;
}

// ---------------------------------------------------------------------------
// K1 (mega): ALL 8 LSTM steps in one kernel. 256 blocks x 512 threads.
// Block owns 16 paths x all 256 units -> recurrence is block-local:
//   h: 8 KB XOR-swizzled LDS buffer (bf16), c: registers (8 f32/lane).
//   x: gathered inline from embedding one step ahead (double-buffered sAx).
//   B: streamed from L2 every step (1 MB/block/step; WfB is L2-resident
//      per-XCD across the whole kernel -- no cross-kernel cold restarts).
// Wave w owns unit-frags {2w, 2w+1}, all 4 gates: per kc 8 MFMAs, B ring
// 4-deep in registers (128 VGPR; lead ~3 kc ~ L2 latency). i,f,g,o of one
// (path,unit) land in the same lane -> register pointwise, c never leaves
// registers. 2 barriers per step. At t=7: per-path max -> logits
// (block-owned, no atomics), h -> h_final (coalesced de-swizzled readout).
// ---------------------------------------------------------------------------
__global__ __launch_bounds__(512, 2)
void mega_kernel(const float* __restrict__ embedding, const int* __restrict__ paths,
                 const unsigned short* __restrict__ WfB, const float* __restrict__ bias,
                 unsigned short* __restrict__ h_final, float* __restrict__ logits) {
    __shared__ __align__(16) short sAx[2][8 * 512];   // x A-frags, double-buffered (16 KB)
    __shared__ __align__(16) short h_lds[16 * 256];   // h (bf16), XOR-swizzled (8 KB)
    __shared__ float red[16 * 8];                     // per-wave row-max partials

    const int tid  = threadIdx.x;
    const int w    = tid >> 6;        // 0..7
    const int lane = tid & 63;
    const int l15  = lane & 15;
    const int quad = lane >> 4;
    const int p0   = blockIdx.x * 16;
    const int unitA = w * 32 + l15;   // unit-frag 2w
    const int unitB = unitA + 16;     // unit-frag 2w+1
    const int boffA = unitA * 32 + quad * 8;
    const int boffB = unitB * 32 + quad * 8;

    float bb[4][2];
#pragma unroll
    for (int g = 0; g < 4; ++g) {
        bb[g][0] = bias[g * 256 + unitA];
        bb[g][1] = bias[g * 256 + unitB];
    }

    // gather x(0): row = tid&15, 8 floats per thread -> one b128 LDS write
    {
        int row = tid & 15, k0 = (tid >> 4) * 8;     // k0 in {0,8,...,248}
        int node = paths[(p0 + row) * LPATH];
        const float* src = embedding + (size_t)node * DIM + k0;
        float4 a = *(const float4*)(src);
        float4 b = *(const float4*)(src + 4);
        short8v pk;
        pk[0]=(short)f2bf(a.x); pk[1]=(short)f2bf(a.y); pk[2]=(short)f2bf(a.z); pk[3]=(short)f2bf(a.w);
        pk[4]=(short)f2bf(b.x); pk[5]=(short)f2bf(b.y); pk[6]=(short)f2bf(b.z); pk[7]=(short)f2bf(b.w);
        int kc = k0 >> 5, q = (k0 >> 3) & 3;
        *(short8v*)(&sAx[0][kc * 512 + (q * 16 + row) * 8]) = pk;
    }

    float cc[4][2] = {{0,0},{0,0},{0,0},{0,0}};
    __syncthreads();

    short8v Bs[4][4][2];                              // [ring slot][gate][uf]
    auto loadBk = [&](int kc, int slot) {
#pragma unroll
        for (int g = 0; g < 4; ++g) {
            size_t cb = (size_t)(g * 16 + kc) * 8192;
            Bs[slot][g][0] = *(const short8v*)(WfB + cb + boffA);
            Bs[slot][g][1] = *(const short8v*)(WfB + cb + boffB);
        }
    };

#pragma unroll 1
    for (int t = 0; t < LPATH; ++t) {
        const bool first = (t == 0), last = (t == LPATH - 1);

        // issue gather of x(t+1) early (consumed after the kc loop)
        float4 gva, gvb;
        int grow = tid & 15, gk0 = (tid >> 4) * 8;
        if (!last) {
            int node = paths[(p0 + grow) * LPATH + t + 1];
            const float* src = embedding + (size_t)node * DIM + gk0;
            gva = *(const float4*)(src);
            gvb = *(const float4*)(src + 4);
        }

        loadBk(0, 0); loadBk(1, 1); loadBk(2, 2); loadBk(3, 3);   // ring prologue

        float4v acc[4][2];
        const float4v z4 = {0.0f, 0.0f, 0.0f, 0.0f};
#pragma unroll
        for (int g = 0; g < 4; ++g) { acc[g][0] = z4; acc[g][1] = z4; }

        const short* sacur = sAx[t & 1];

        auto kstep = [&](int kc, short8v a) {
#pragma unroll
            for (int g = 0; g < 4; ++g) {
                acc[g][0] = __builtin_amdgcn_mfma_f32_16x16x32_bf16(a, Bs[kc & 3][g][0], acc[g][0], 0, 0, 0);
                acc[g][1] = __builtin_amdgcn_mfma_f32_16x16x32_bf16(a, Bs[kc & 3][g][1], acc[g][1], 0, 0, 0);
            }
        };

        if (first) {
#pragma unroll
            for (int kc = 0; kc < 8; ++kc) {          // h==0: x-half only
                short8v a = *(const short8v*)(sacur + kc * 512 + lane * 8);
                kstep(kc, a);
                if (kc + 4 < 8) loadBk(kc + 4, kc & 3);
            }
        } else {
#pragma unroll
            for (int kc = 0; kc < 16; ++kc) {
                short8v a;
                if (kc < 8) {
                    a = *(const short8v*)(sacur + kc * 512 + lane * 8);
                } else {
                    int kcp = kc - 8;
                    int cg  = kcp * 4 + quad;         // 16-B group of h row
                    int cgs = cg ^ (l15 & 7);         // XOR swizzle (bank-spread)
                    a = *(const short8v*)(&h_lds[l15 * 256 + cgs * 8]);
                }
                kstep(kc, a);
                if (kc + 4 < 16) loadBk(kc + 4, kc & 3);
            }
        }

        // stage sAx[next] (that buffer's reads finished a full step ago)
        if (!last) {
            short8v pk;
            pk[0]=(short)f2bf(gva.x); pk[1]=(short)f2bf(gva.y); pk[2]=(short)f2bf(gva.z); pk[3]=(short)f2bf(gva.w);
            pk[4]=(short)f2bf(gvb.x); pk[5]=(short)f2bf(gvb.y); pk[6]=(short)f2bf(gvb.z); pk[7]=(short)f2bf(gvb.w);
            int kc = gk0 >> 5, q = (gk0 >> 3) & 3;
            *(short8v*)(&sAx[(t + 1) & 1][kc * 512 + (q * 16 + grow) * 8]) = pk;
        }

        // pointwise LSTM update: 8 cells/lane, c persistent in registers
        float hv[4][2];
#pragma unroll
        for (int r = 0; r < 4; ++r) {
#pragma unroll
            for (int e = 0; e < 2; ++e) {
                float iv = acc[0][e][r] + bb[0][e];
                float fv = acc[1][e][r] + bb[1][e];
                float gg = acc[2][e][r] + bb[2][e];
                float ov = acc[3][e][r] + bb[3][e];
                float cn = fast_sigmoid(fv) * cc[r][e] + fast_sigmoid(iv) * fast_tanh(gg);
                cc[r][e] = cn;
                hv[r][e] = fast_sigmoid(ov) * fast_tanh(cn);
            }
        }

        __syncthreads();   // barrier B: all reads of h_lds / sAx[cur] done

        // write new h into h_lds (same XOR swizzle as the read side)
#pragma unroll
        for (int r = 0; r < 4; ++r) {
            int pr = quad * 4 + r;
#pragma unroll
            for (int e = 0; e < 2; ++e) {
                int u   = (e == 0) ? unitA : unitB;
                int cgs = (u >> 3) ^ (pr & 7);
                h_lds[pr * 256 + cgs * 8 + (u & 7)] = (short)f2bf(hv[r][e]);
            }
        }

        if (last) {
            // per-path max over this wave's 32 units -> LDS partials
#pragma unroll
            for (int r = 0; r < 4; ++r) {
                float m = fmaxf(hv[r][0], hv[r][1]);
                m = fmaxf(m, __shfl_xor(m, 1, 64));
                m = fmaxf(m, __shfl_xor(m, 2, 64));
                m = fmaxf(m, __shfl_xor(m, 4, 64));
                m = fmaxf(m, __shfl_xor(m, 8, 64));
                if (l15 == 0) red[(quad * 4 + r) * 8 + w] = m;
            }
        }
        __syncthreads();   // barrier A': h_lds (and red) visible
    }

    // logits: block-owned paths -> plain stores, no atomics
    if (tid < 16) {
        float m = red[tid * 8];
#pragma unroll
        for (int j = 1; j < 8; ++j) m = fmaxf(m, red[tid * 8 + j]);
        logits[p0 + tid] = m;
    }
    // h_final writeback, coalesced: de-swizzle (group i5 of row lives at
    // swizzled slot cgs = i5 ^ (row&7); store it at its TRUE offset i5*8).
    {
        int row = tid >> 5, i5 = tid & 31;
        int cgs = i5 ^ (row & 7);
        short8v v = *(const short8v*)(&h_lds[row * 256 + cgs * 8]);
        *(short8v*)(h_final + (size_t)(p0 + row) * HID + (size_t)i5 * 8) = v;
    }
}

// ---------------------------------------------------------------------------
// K2: fused softmax + attention + (last block) final linear+sigmoid.
// 256 blocks x 256 threads; each block redundantly computes the global
// softmax scalars from the 16 KB logits array, accumulates its 16 paths
// into path_emb, then the LAST block (device-scope ticket, properly
// fenced+barriered) computes out.
// ---------------------------------------------------------------------------
__global__ void attn_final_kernel(const unsigned short* __restrict__ h_final,
                                  const float* __restrict__ logits,
                                  float* __restrict__ path_emb,
                                  unsigned int* __restrict__ done,
                                  const float* __restrict__ embedding,
                                  const int* __restrict__ user_id,
                                  const int* __restrict__ item_id,
                                  const float* __restrict__ w_lin,
                                  const float* __restrict__ b_lin,
                                  float* __restrict__ out) {
    __shared__ float red[256];
    __shared__ float wts[16];
    __shared__ int lastf;
    int tid = threadIdx.x;
    int p0  = blockIdx.x * 16;

    float vals[16];
    float m = -1e30f;
#pragma unroll
    for (int i = 0; i < 16; ++i) {
        vals[i] = logits[i * 256 + tid];
        m = fmaxf(m, vals[i]);
    }
    red[tid] = m; __syncthreads();
    for (int s = 128; s > 0; s >>= 1) {
        if (tid < s) red[tid] = fmaxf(red[tid], red[tid + s]);
        __syncthreads();
    }
    m = red[0]; __syncthreads();
    float sum = 0.0f;
#pragma unroll
    for (int i = 0; i < 16; ++i) sum += __expf(vals[i] - m);
    red[tid] = sum; __syncthreads();
    for (int s = 128; s > 0; s >>= 1) {
        if (tid < s) red[tid] += red[tid + s];
        __syncthreads();
    }
    if (tid == 0) red[0] = 1.0f / red[0];
    __syncthreads();
    float invZ = red[0];
    if (tid < 16) wts[tid] = __expf(logits[p0 + tid] - m) * invZ;
    __syncthreads();

    float acc = 0.0f;
#pragma unroll
    for (int j = 0; j < 16; ++j)
        acc += wts[j] * bf2f(h_final[(size_t)(p0 + j) * HID + tid]);
    atomicAdd(&path_emb[tid], acc);

    // release: every thread's add made visible, then whole block synced,
    // THEN the ticket increments (R2 bug: ticket raced ahead of adds).
    __threadfence();
    __syncthreads();
    if (tid == 0) {
        unsigned int old = atomicAdd(done, 1u);
        lastf = (old == 255u) ? 1 : 0;
    }
    __syncthreads();
    if (lastf) {
        __threadfence();                 // acquire all blocks' partials
        float pe = __hip_atomic_load(&path_emb[tid], __ATOMIC_RELAXED,
                                     __HIP_MEMORY_SCOPE_AGENT);
        int u  = user_id[0];
        int it = item_id[0];
        float s = w_lin[tid]       * embedding[(size_t)u  * DIM + tid]
                + w_lin[256 + tid] * embedding[(size_t)it * DIM + tid]
                + w_lin[512 + tid] * pe;
        red[tid] = s; __syncthreads();
        for (int st = 128; st > 0; st >>= 1) {
            if (tid < st) red[tid] += red[tid + st];
            __syncthreads();
        }
        if (tid == 0) out[0] = 1.0f / (1.0f + __expf(-(red[0] + b_lin[0])));
    }
}

// ---------------------------------------------------------------------------
extern "C" void kernel_launch(void* const* d_in, const int* in_sizes, int n_in,
                              void* d_out, int out_size, void* d_ws, size_t ws_size,
                              hipStream_t stream) {
    const float* embedding = (const float*)d_in[0];
    const float* w_ih      = (const float*)d_in[1];
    const float* w_hh      = (const float*)d_in[2];
    const float* b_ih      = (const float*)d_in[3];
    const float* b_hh      = (const float*)d_in[4];
    const float* w_lin     = (const float*)d_in[5];
    const float* b_lin     = (const float*)d_in[6];
    const int*   paths     = (const int*)d_in[7];
    const int*   user_id   = (const int*)d_in[8];
    const int*   item_id   = (const int*)d_in[9];
    float* outp = (float*)d_out;

    // workspace layout (~3.1 MB), 256-B aligned
    char* ws = (char*)d_ws;
    size_t off = 0;
    auto alloc = [&](size_t n) { void* p = ws + off; off = (off + n + 255) & ~(size_t)255; return p; };
    unsigned short* WfB      = (unsigned short*)alloc((size_t)1024 * 512 * 2);   // 1 MB
    float*          bias     = (float*)alloc(1024 * 4);                          // 4 KB
    float*          path_emb = (float*)alloc(HID * 4);                           // 1 KB
    float*          logits   = (float*)alloc(NPATHS * 4);                        // 16 KB
    unsigned short* h_final  = (unsigned short*)alloc((size_t)NPATHS * HID * 2); // 2 MB
    unsigned int*   done     = (unsigned int*)alloc(4);

    prep_kernel<<<512, 256, 0, stream>>>(w_ih, w_hh, b_ih, b_hh, WfB, bias,
                                         path_emb, done);

    mega_kernel<<<256, 512, 0, stream>>>(embedding, paths, WfB, bias,
                                         h_final, logits);

    attn_final_kernel<<<256, 256, 0, stream>>>(h_final, logits, path_emb, done,
                                               embedding, user_id, item_id,
                                               w_lin, b_lin, outp);
}

// Round 4
// 426.988 us; speedup vs baseline: 1.2400x; 1.2400x over previous
//
#include <hip/hip_runtime.h>
#include <stdint.h>

#define NPATHS 4096
#define LPATH  8
#define DIM    256
#define HID    256

typedef short  short4v __attribute__((ext_vector_type(4)));
typedef short  short8v __attribute__((ext_vector_type(8)));
typedef float  float4v __attribute__((ext_vector_type(4)));

__device__ __forceinline__ unsigned short f2bf(float f) {
    union { float f; uint32_t u; } v; v.f = f;
    uint32_t u = v.u;
    u += 0x7FFFu + ((u >> 16) & 1u);   // round-to-nearest-even
    return (unsigned short)(u >> 16);
}
__device__ __forceinline__ float bf2f(unsigned short s) {
    return __uint_as_float(((uint32_t)s) << 16);
}
__device__ __forceinline__ float fast_sigmoid(float x) {
    return 1.0f / (1.0f + __expf(-x));
}
__device__ __forceinline__ float fast_tanh(float x) {
    x = fminf(15.0f, fmaxf(-15.0f, x));
    float e = __expf(2.0f * x);
    return (e - 1.0f) / (e + 1.0f);
}

// ---------------------------------------------------------------------------
// K0: pack weights into B-fragment order + bias + zero path_emb/done.
// WfB (shorts): [(g*16+kc)][unit][quad*8+j] -> step wave load is coalesced.
// ---------------------------------------------------------------------------
__global__ void prep_kernel(const float* __restrict__ w_ih, const float* __restrict__ w_hh,
                            const float* __restrict__ b_ih, const float* __restrict__ b_hh,
                            unsigned short* __restrict__ WfB, float* __restrict__ bias,
                            float* __restrict__ path_emb, unsigned int* __restrict__ done) {
    int gid  = blockIdx.x * 256 + threadIdx.x;    // 0..131071
    int base = gid * 4;                           // short index, %4==0
    int j0   = base & 31;                         // quad*8+j
    int unit = (base >> 5) & 255;
    int gkc  = base >> 13;                        // g*16+kc, 0..63
    int g    = gkc >> 4, kc = gkc & 15;
    int row  = g * 256 + unit;
    int k    = kc * 32 + j0;
    const float* src = (k < DIM) ? (w_ih + (size_t)row * DIM + k)
                                 : (w_hh + (size_t)row * HID + (k - DIM));
    float4 v = *(const float4*)src;
    short4v pk = {(short)f2bf(v.x), (short)f2bf(v.y), (short)f2bf(v.z), (short)f2bf(v.w)};
    *(short4v*)(WfB + base) = pk;
    if (gid < 1024) bias[gid] = b_ih[gid] + b_hh[gid];
    if (gid < 256)  path_emb[gid] = 0.0f;
    if (gid == 0)   *done = 0u;
}

// ---------------------------------------------------------------------------
// K1 (mega): ALL 8 LSTM steps in one kernel. 256 blocks x 1024 threads
// (16 waves, 4/SIMD, VGPR cap 128 -- per-wave state sized to ~100 so the
// R3 scratch-spill catastrophe (356 MB fetch / 92 MB write) cannot recur).
// Block owns 16 paths x all 256 units -> recurrence is block-local:
//   h: 8 KB XOR-swizzled LDS (bf16), c: registers (4 f32/lane).
//   x: gathered inline one step ahead via NONTEMPORAL loads (no L2 reuse,
//      and nt keeps the gather stream from evicting L2-resident WfB).
//   B: streamed from L2 every step (1 MB/block/step; per-CU L2 port is the
//      expected bound: 8 MB/block over the kernel ~ 58 us).
// Wave w owns unit-frag w (units 16w..16w+15), all 4 gates: per kc 4 MFMAs,
// B ring 2-deep = 32 VGPR. i,f,g,o of one (path,unit) land in the same lane
// -> register pointwise, c never leaves registers. 2 barriers per step.
// Next-step B prologue loads are hoisted before the barriers (B addresses
// are t-invariant) so the L2 port stays busy across the sync points.
// At t=7: per-path max -> logits (block-owned, no atomics), h -> h_final.
// ---------------------------------------------------------------------------
__global__ __launch_bounds__(1024, 4)
void mega_kernel(const float* __restrict__ embedding, const int* __restrict__ paths,
                 const unsigned short* __restrict__ WfB, const float* __restrict__ bias,
                 unsigned short* __restrict__ h_final, float* __restrict__ logits) {
    __shared__ __align__(16) short sAx[2][8 * 512];   // x A-frags, double-buffered (16 KB)
    __shared__ __align__(16) short h_lds[16 * 256];   // h (bf16), XOR-swizzled (8 KB)
    __shared__ float red[16 * 16];                    // per-wave row-max partials

    const int tid  = threadIdx.x;
    const int w    = tid >> 6;        // 0..15
    const int lane = tid & 63;
    const int l15  = lane & 15;
    const int quad = lane >> 4;
    const int p0   = blockIdx.x * 16;
    const int unit = w * 16 + l15;    // this wave's unit-frag
    const unsigned short* wbase = WfB + unit * 32 + quad * 8;

    float bb[4];
#pragma unroll
    for (int g = 0; g < 4; ++g) bb[g] = bias[g * 256 + unit];

    // gather x(0): 4 floats/thread -> one b64 LDS write (fragment order)
    const int grow = tid & 15;            // path row
    const int gk0  = (tid >> 4) * 4;      // k offset 0..252
    const int gdst = (gk0 >> 5) * 512 + (((gk0 >> 3) & 3) * 16 + grow) * 8 + (gk0 & 4);
    {
        int node = paths[(p0 + grow) * LPATH];
        float4v v = __builtin_nontemporal_load(
            (const float4v*)(embedding + (size_t)node * DIM + gk0));
        short4v pk = {(short)f2bf(v[0]), (short)f2bf(v[1]),
                      (short)f2bf(v[2]), (short)f2bf(v[3])};
        *(short4v*)(&sAx[0][gdst]) = pk;
    }

    float cc[4] = {0.0f, 0.0f, 0.0f, 0.0f};

    short8v Bs[2][4];                     // 2-deep kc ring, 32 VGPR
    auto loadBk = [&](int kc, int slot) {
#pragma unroll
        for (int g = 0; g < 4; ++g)
            Bs[slot][g] = *(const short8v*)(wbase + (size_t)(g * 16 + kc) * 8192);
    };
    loadBk(0, 0); loadBk(1, 1);           // prologue for t=0

    __syncthreads();                      // x(0) staged

#pragma unroll 1
    for (int t = 0; t < LPATH; ++t) {
        const bool first = (t == 0), last = (t == LPATH - 1);

        // issue gather of x(t+1) early (nontemporal; consumed after kc loop)
        float4v gv;
        if (!last) {
            int node = paths[(p0 + grow) * LPATH + t + 1];
            gv = __builtin_nontemporal_load(
                (const float4v*)(embedding + (size_t)node * DIM + gk0));
        }

        float4v acc[4];
        const float4v z4 = {0.0f, 0.0f, 0.0f, 0.0f};
#pragma unroll
        for (int g = 0; g < 4; ++g) acc[g] = z4;

        const short* sacur = sAx[t & 1];

        auto kstep = [&](int kc, short8v a) {
#pragma unroll
            for (int g = 0; g < 4; ++g)
                acc[g] = __builtin_amdgcn_mfma_f32_16x16x32_bf16(
                    a, Bs[kc & 1][g], acc[g], 0, 0, 0);
        };

        if (first) {
#pragma unroll
            for (int kc = 0; kc < 8; ++kc) {          // h==0: x-half only
                short8v a = *(const short8v*)(sacur + kc * 512 + lane * 8);
                kstep(kc, a);
                if (kc + 2 < 8) loadBk(kc + 2, kc & 1);
            }
        } else {
#pragma unroll
            for (int kc = 0; kc < 16; ++kc) {
                short8v a;
                if (kc < 8) {
                    a = *(const short8v*)(sacur + kc * 512 + lane * 8);
                } else {
                    int cg  = (kc - 8) * 4 + quad;    // 16-B group of h row
                    int cgs = cg ^ (l15 & 7);         // XOR swizzle (bank-spread)
                    a = *(const short8v*)(&h_lds[l15 * 256 + cgs * 8]);
                }
                kstep(kc, a);
                if (kc + 2 < 16) loadBk(kc + 2, kc & 1);
            }
        }

        // hoisted next-step ring prologue (B addrs t-invariant; keeps the
        // L2 port busy across the two barriers below)
        if (!last) { loadBk(0, 0); loadBk(1, 1); }

        // stage sAx[next] (that buffer's reads finished a full step ago)
        if (!last) {
            short4v pk = {(short)f2bf(gv[0]), (short)f2bf(gv[1]),
                          (short)f2bf(gv[2]), (short)f2bf(gv[3])};
            *(short4v*)(&sAx[(t + 1) & 1][gdst]) = pk;
        }

        // pointwise LSTM update: 4 cells/lane, c persistent in registers
        float hv[4];
#pragma unroll
        for (int r = 0; r < 4; ++r) {
            float iv = acc[0][r] + bb[0];
            float fv = acc[1][r] + bb[1];
            float gg = acc[2][r] + bb[2];
            float ov = acc[3][r] + bb[3];
            float cn = fast_sigmoid(fv) * cc[r] + fast_sigmoid(iv) * fast_tanh(gg);
            cc[r] = cn;
            hv[r] = fast_sigmoid(ov) * fast_tanh(cn);
        }

        __syncthreads();   // barrier B: all reads of h_lds / sAx[cur] done

        // write new h into h_lds (same XOR swizzle as the read side)
#pragma unroll
        for (int r = 0; r < 4; ++r) {
            int pr  = quad * 4 + r;
            int cgs = (unit >> 3) ^ (pr & 7);
            h_lds[pr * 256 + cgs * 8 + (unit & 7)] = (short)f2bf(hv[r]);
        }

        if (last) {
            // per-path max over this wave's 16 units -> LDS partials
#pragma unroll
            for (int r = 0; r < 4; ++r) {
                float m = hv[r];
                m = fmaxf(m, __shfl_xor(m, 1, 64));
                m = fmaxf(m, __shfl_xor(m, 2, 64));
                m = fmaxf(m, __shfl_xor(m, 4, 64));
                m = fmaxf(m, __shfl_xor(m, 8, 64));
                if (l15 == 0) red[(quad * 4 + r) * 16 + w] = m;
            }
        }
        __syncthreads();   // barrier A': h_lds (and red) visible
    }

    // logits: block-owned paths -> plain stores, no atomics
    if (tid < 16) {
        float m = red[tid * 16];
#pragma unroll
        for (int j = 1; j < 16; ++j) m = fmaxf(m, red[tid * 16 + j]);
        logits[p0 + tid] = m;
    }
    // h_final writeback, coalesced: de-swizzle (group i5 of row lives at
    // swizzled slot cgs = i5 ^ (row&7); store it at its TRUE offset i5*8).
    if (tid < 512) {
        int row = tid >> 5, i5 = tid & 31;
        int cgs = i5 ^ (row & 7);
        short8v v = *(const short8v*)(&h_lds[row * 256 + cgs * 8]);
        *(short8v*)(h_final + (size_t)(p0 + row) * HID + (size_t)i5 * 8) = v;
    }
}

// ---------------------------------------------------------------------------
// K2: fused softmax + attention + (last block) final linear+sigmoid.
// 256 blocks x 256 threads; each block redundantly computes the global
// softmax scalars from the 16 KB logits array, accumulates its 16 paths
// into path_emb, then the LAST block (device-scope ticket, properly
// fenced+barriered) computes out.
// ---------------------------------------------------------------------------
__global__ void attn_final_kernel(const unsigned short* __restrict__ h_final,
                                  const float* __restrict__ logits,
                                  float* __restrict__ path_emb,
                                  unsigned int* __restrict__ done,
                                  const float* __restrict__ embedding,
                                  const int* __restrict__ user_id,
                                  const int* __restrict__ item_id,
                                  const float* __restrict__ w_lin,
                                  const float* __restrict__ b_lin,
                                  float* __restrict__ out) {
    __shared__ float red[256];
    __shared__ float wts[16];
    __shared__ int lastf;
    int tid = threadIdx.x;
    int p0  = blockIdx.x * 16;

    float vals[16];
    float m = -1e30f;
#pragma unroll
    for (int i = 0; i < 16; ++i) {
        vals[i] = logits[i * 256 + tid];
        m = fmaxf(m, vals[i]);
    }
    red[tid] = m; __syncthreads();
    for (int s = 128; s > 0; s >>= 1) {
        if (tid < s) red[tid] = fmaxf(red[tid], red[tid + s]);
        __syncthreads();
    }
    m = red[0]; __syncthreads();
    float sum = 0.0f;
#pragma unroll
    for (int i = 0; i < 16; ++i) sum += __expf(vals[i] - m);
    red[tid] = sum; __syncthreads();
    for (int s = 128; s > 0; s >>= 1) {
        if (tid < s) red[tid] += red[tid + s];
        __syncthreads();
    }
    if (tid == 0) red[0] = 1.0f / red[0];
    __syncthreads();
    float invZ = red[0];
    if (tid < 16) wts[tid] = __expf(logits[p0 + tid] - m) * invZ;
    __syncthreads();

    float acc = 0.0f;
#pragma unroll
    for (int j = 0; j < 16; ++j)
        acc += wts[j] * bf2f(h_final[(size_t)(p0 + j) * HID + tid]);
    atomicAdd(&path_emb[tid], acc);

    // release: every thread's add made visible, then whole block synced,
    // THEN the ticket increments.
    __threadfence();
    __syncthreads();
    if (tid == 0) {
        unsigned int old = atomicAdd(done, 1u);
        lastf = (old == 255u) ? 1 : 0;
    }
    __syncthreads();
    if (lastf) {
        __threadfence();                 // acquire all blocks' partials
        float pe = __hip_atomic_load(&path_emb[tid], __ATOMIC_RELAXED,
                                     __HIP_MEMORY_SCOPE_AGENT);
        int u  = user_id[0];
        int it = item_id[0];
        float s = w_lin[tid]       * embedding[(size_t)u  * DIM + tid]
                + w_lin[256 + tid] * embedding[(size_t)it * DIM + tid]
                + w_lin[512 + tid] * pe;
        red[tid] = s; __syncthreads();
        for (int st = 128; st > 0; st >>= 1) {
            if (tid < st) red[tid] += red[tid + st];
            __syncthreads();
        }
        if (tid == 0) out[0] = 1.0f / (1.0f + __expf(-(red[0] + b_lin[0])));
    }
}

// ---------------------------------------------------------------------------
extern "C" void kernel_launch(void* const* d_in, const int* in_sizes, int n_in,
                              void* d_out, int out_size, void* d_ws, size_t ws_size,
                              hipStream_t stream) {
    const float* embedding = (const float*)d_in[0];
    const float* w_ih      = (const float*)d_in[1];
    const float* w_hh      = (const float*)d_in[2];
    const float* b_ih      = (const float*)d_in[3];
    const float* b_hh      = (const float*)d_in[4];
    const float* w_lin     = (const float*)d_in[5];
    const float* b_lin     = (const float*)d_in[6];
    const int*   paths     = (const int*)d_in[7];
    const int*   user_id   = (const int*)d_in[8];
    const int*   item_id   = (const int*)d_in[9];
    float* outp = (float*)d_out;

    // workspace layout (~3.1 MB), 256-B aligned
    char* ws = (char*)d_ws;
    size_t off = 0;
    auto alloc = [&](size_t n) { void* p = ws + off; off = (off + n + 255) & ~(size_t)255; return p; };
    unsigned short* WfB      = (unsigned short*)alloc((size_t)1024 * 512 * 2);   // 1 MB
    float*          bias     = (float*)alloc(1024 * 4);                          // 4 KB
    float*          path_emb = (float*)alloc(HID * 4);                           // 1 KB
    float*          logits   = (float*)alloc(NPATHS * 4);                        // 16 KB
    unsigned short* h_final  = (unsigned short*)alloc((size_t)NPATHS * HID * 2); // 2 MB
    unsigned int*   done     = (unsigned int*)alloc(4);

    prep_kernel<<<512, 256, 0, stream>>>(w_ih, w_hh, b_ih, b_hh, WfB, bias,
                                         path_emb, done);

    mega_kernel<<<256, 1024, 0, stream>>>(embedding, paths, WfB, bias,
                                          h_final, logits);

    attn_final_kernel<<<256, 256, 0, stream>>>(h_final, logits, path_emb, done,
                                               embedding, user_id, item_id,
                                               w_lin, b_lin, outp);
}

// Round 5
// 426.575 us; speedup vs baseline: 1.2412x; 1.0010x over previous
//
#include <hip/hip_runtime.h>
#include <stdint.h>

#define NPATHS 4096
#define LPATH  8
#define DIM    256
#define HID    256

typedef short  short4v __attribute__((ext_vector_type(4)));
typedef short  short8v __attribute__((ext_vector_type(8)));
typedef float  float4v __attribute__((ext_vector_type(4)));

__device__ __forceinline__ unsigned short f2bf(float f) {
    union { float f; uint32_t u; } v; v.f = f;
    uint32_t u = v.u;
    u += 0x7FFFu + ((u >> 16) & 1u);   // round-to-nearest-even
    return (unsigned short)(u >> 16);
}
__device__ __forceinline__ float bf2f(unsigned short s) {
    return __uint_as_float(((uint32_t)s) << 16);
}
__device__ __forceinline__ float fast_sigmoid(float x) {
    return 1.0f / (1.0f + __expf(-x));
}
__device__ __forceinline__ float fast_tanh(float x) {
    x = fminf(15.0f, fmaxf(-15.0f, x));
    float e = __expf(2.0f * x);
    return (e - 1.0f) / (e + 1.0f);
}

// ---------------------------------------------------------------------------
// K0: pack weights into B-fragment order + bias + zero path_emb/done.
// WfB (shorts): [(g*16+kc)][unit][quad*8+j] -> step wave load is coalesced.
// ---------------------------------------------------------------------------
__global__ void prep_kernel(const float* __restrict__ w_ih, const float* __restrict__ w_hh,
                            const float* __restrict__ b_ih, const float* __restrict__ b_hh,
                            unsigned short* __restrict__ WfB, float* __restrict__ bias,
                            float* __restrict__ path_emb, unsigned int* __restrict__ done) {
    int gid  = blockIdx.x * 256 + threadIdx.x;    // 0..131071
    int base = gid * 4;                           // short index, %4==0
    int j0   = base & 31;                         // quad*8+j
    int unit = (base >> 5) & 255;
    int gkc  = base >> 13;                        // g*16+kc, 0..63
    int g    = gkc >> 4, kc = gkc & 15;
    int row  = g * 256 + unit;
    int k    = kc * 32 + j0;
    const float* src = (k < DIM) ? (w_ih + (size_t)row * DIM + k)
                                 : (w_hh + (size_t)row * HID + (k - DIM));
    float4 v = *(const float4*)src;
    short4v pk = {(short)f2bf(v.x), (short)f2bf(v.y), (short)f2bf(v.z), (short)f2bf(v.w)};
    *(short4v*)(WfB + base) = pk;
    if (gid < 1024) bias[gid] = b_ih[gid] + b_hh[gid];
    if (gid < 256)  path_emb[gid] = 0.0f;
    if (gid == 0)   *done = 0u;
}

// ---------------------------------------------------------------------------
// K1 (mega): ALL 8 LSTM steps in one kernel. 256 blocks x 1024 threads.
//
// LAUNCH-BOUNDS LESSON (R3/R4 counters): hipcc's 2nd __launch_bounds__ arg
// behaves as min WORKGROUPS PER CU (CUDA semantics). (512,2) gave a 128-VGPR
// cap; (1024,4) clamped to 2 blocks/CU = 8 waves/SIMD and a 64-VGPR cap ->
// ~40 VGPR/lane of state spilled to scratch INSIDE the kc loop (554 MB fetch
// / 140 MB write, 288 us). (1024,1) = 1 block/CU = 4 waves/SIMD = 128-VGPR
// cap, which fits the ~100-VGPR/wave demand with zero spill.
//
// Block owns 16 paths x all 256 units -> recurrence is block-local:
//   h: 8 KB XOR-swizzled LDS (bf16), c: registers (4 f32/lane).
//   x: gathered inline one step ahead via NONTEMPORAL loads.
//   B: streamed from L2 every step (1 MB/block/step; ~8 MB/CU total over
//      the kernel at ~64 B/cyc/CU L1-return ~ 55 us expected floor).
// Wave w owns unit-frag w (units 16w..16w+15), all 4 gates: per kc 4 MFMAs,
// B ring 2-deep = 32 VGPR. i,f,g,o of one (path,unit) land in the same lane
// -> register pointwise, c never leaves registers. 2 barriers per step.
// At t=7: per-path max -> logits (block-owned, no atomics), h -> h_final.
// ---------------------------------------------------------------------------
__global__ __launch_bounds__(1024, 1)
void mega_kernel(const float* __restrict__ embedding, const int* __restrict__ paths,
                 const unsigned short* __restrict__ WfB, const float* __restrict__ bias,
                 unsigned short* __restrict__ h_final, float* __restrict__ logits) {
    __shared__ __align__(16) short sAx[2][8 * 512];   // x A-frags, double-buffered (16 KB)
    __shared__ __align__(16) short h_lds[16 * 256];   // h (bf16), XOR-swizzled (8 KB)
    __shared__ float red[16 * 16];                    // per-wave row-max partials

    const int tid  = threadIdx.x;
    const int w    = tid >> 6;        // 0..15
    const int lane = tid & 63;
    const int l15  = lane & 15;
    const int quad = lane >> 4;
    const int p0   = blockIdx.x * 16;
    const int unit = w * 16 + l15;    // this wave's unit-frag
    const unsigned short* wbase = WfB + unit * 32 + quad * 8;

    float bb[4];
#pragma unroll
    for (int g = 0; g < 4; ++g) bb[g] = bias[g * 256 + unit];

    // gather x(0): 4 floats/thread -> one b64 LDS write (fragment order)
    const int grow = tid & 15;            // path row
    const int gk0  = (tid >> 4) * 4;      // k offset 0..252
    const int gdst = (gk0 >> 5) * 512 + (((gk0 >> 3) & 3) * 16 + grow) * 8 + (gk0 & 4);
    {
        int node = paths[(p0 + grow) * LPATH];
        float4v v = __builtin_nontemporal_load(
            (const float4v*)(embedding + (size_t)node * DIM + gk0));
        short4v pk = {(short)f2bf(v[0]), (short)f2bf(v[1]),
                      (short)f2bf(v[2]), (short)f2bf(v[3])};
        *(short4v*)(&sAx[0][gdst]) = pk;
    }

    float cc[4] = {0.0f, 0.0f, 0.0f, 0.0f};

    short8v Bs[2][4];                     // 2-deep kc ring, 32 VGPR
    auto loadBk = [&](int kc, int slot) {
#pragma unroll
        for (int g = 0; g < 4; ++g)
            Bs[slot][g] = *(const short8v*)(wbase + (size_t)(g * 16 + kc) * 8192);
    };
    loadBk(0, 0); loadBk(1, 1);           // prologue for t=0

    __syncthreads();                      // x(0) staged

#pragma unroll 1
    for (int t = 0; t < LPATH; ++t) {
        const bool first = (t == 0), last = (t == LPATH - 1);

        // issue gather of x(t+1) early (nontemporal; consumed after kc loop)
        float4v gv;
        if (!last) {
            int node = paths[(p0 + grow) * LPATH + t + 1];
            gv = __builtin_nontemporal_load(
                (const float4v*)(embedding + (size_t)node * DIM + gk0));
        }

        float4v acc[4];
        const float4v z4 = {0.0f, 0.0f, 0.0f, 0.0f};
#pragma unroll
        for (int g = 0; g < 4; ++g) acc[g] = z4;

        const short* sacur = sAx[t & 1];

        auto kstep = [&](int kc, short8v a) {
#pragma unroll
            for (int g = 0; g < 4; ++g)
                acc[g] = __builtin_amdgcn_mfma_f32_16x16x32_bf16(
                    a, Bs[kc & 1][g], acc[g], 0, 0, 0);
        };

        if (first) {
#pragma unroll
            for (int kc = 0; kc < 8; ++kc) {          // h==0: x-half only
                short8v a = *(const short8v*)(sacur + kc * 512 + lane * 8);
                kstep(kc, a);
                if (kc + 2 < 8) loadBk(kc + 2, kc & 1);
            }
        } else {
#pragma unroll
            for (int kc = 0; kc < 16; ++kc) {
                short8v a;
                if (kc < 8) {
                    a = *(const short8v*)(sacur + kc * 512 + lane * 8);
                } else {
                    int cg  = (kc - 8) * 4 + quad;    // 16-B group of h row
                    int cgs = cg ^ (l15 & 7);         // XOR swizzle (bank-spread)
                    a = *(const short8v*)(&h_lds[l15 * 256 + cgs * 8]);
                }
                kstep(kc, a);
                if (kc + 2 < 16) loadBk(kc + 2, kc & 1);
            }
        }

        // hoisted next-step ring prologue (B addrs t-invariant; keeps the
        // L2 port busy across the two barriers below)
        if (!last) { loadBk(0, 0); loadBk(1, 1); }

        // stage sAx[next] (that buffer's reads finished a full step ago)
        if (!last) {
            short4v pk = {(short)f2bf(gv[0]), (short)f2bf(gv[1]),
                          (short)f2bf(gv[2]), (short)f2bf(gv[3])};
            *(short4v*)(&sAx[(t + 1) & 1][gdst]) = pk;
        }

        // pointwise LSTM update: 4 cells/lane, c persistent in registers
        float hv[4];
#pragma unroll
        for (int r = 0; r < 4; ++r) {
            float iv = acc[0][r] + bb[0];
            float fv = acc[1][r] + bb[1];
            float gg = acc[2][r] + bb[2];
            float ov = acc[3][r] + bb[3];
            float cn = fast_sigmoid(fv) * cc[r] + fast_sigmoid(iv) * fast_tanh(gg);
            cc[r] = cn;
            hv[r] = fast_sigmoid(ov) * fast_tanh(cn);
        }

        __syncthreads();   // barrier B: all reads of h_lds / sAx[cur] done

        // write new h into h_lds (same XOR swizzle as the read side)
#pragma unroll
        for (int r = 0; r < 4; ++r) {
            int pr  = quad * 4 + r;
            int cgs = (unit >> 3) ^ (pr & 7);
            h_lds[pr * 256 + cgs * 8 + (unit & 7)] = (short)f2bf(hv[r]);
        }

        if (last) {
            // per-path max over this wave's 16 units -> LDS partials
#pragma unroll
            for (int r = 0; r < 4; ++r) {
                float m = hv[r];
                m = fmaxf(m, __shfl_xor(m, 1, 64));
                m = fmaxf(m, __shfl_xor(m, 2, 64));
                m = fmaxf(m, __shfl_xor(m, 4, 64));
                m = fmaxf(m, __shfl_xor(m, 8, 64));
                if (l15 == 0) red[(quad * 4 + r) * 16 + w] = m;
            }
        }
        __syncthreads();   // barrier A': h_lds (and red) visible
    }

    // logits: block-owned paths -> plain stores, no atomics
    if (tid < 16) {
        float m = red[tid * 16];
#pragma unroll
        for (int j = 1; j < 16; ++j) m = fmaxf(m, red[tid * 16 + j]);
        logits[p0 + tid] = m;
    }
    // h_final writeback, coalesced: de-swizzle (group i5 of row lives at
    // swizzled slot cgs = i5 ^ (row&7); store it at its TRUE offset i5*8).
    if (tid < 512) {
        int row = tid >> 5, i5 = tid & 31;
        int cgs = i5 ^ (row & 7);
        short8v v = *(const short8v*)(&h_lds[row * 256 + cgs * 8]);
        *(short8v*)(h_final + (size_t)(p0 + row) * HID + (size_t)i5 * 8) = v;
    }
}

// ---------------------------------------------------------------------------
// K2: fused softmax + attention + (last block) final linear+sigmoid.
// 256 blocks x 256 threads; each block redundantly computes the global
// softmax scalars from the 16 KB logits array, accumulates its 16 paths
// into path_emb, then the LAST block (device-scope ticket, properly
// fenced+barriered) computes out.
// ---------------------------------------------------------------------------
__global__ void attn_final_kernel(const unsigned short* __restrict__ h_final,
                                  const float* __restrict__ logits,
                                  float* __restrict__ path_emb,
                                  unsigned int* __restrict__ done,
                                  const float* __restrict__ embedding,
                                  const int* __restrict__ user_id,
                                  const int* __restrict__ item_id,
                                  const float* __restrict__ w_lin,
                                  const float* __restrict__ b_lin,
                                  float* __restrict__ out) {
    __shared__ float red[256];
    __shared__ float wts[16];
    __shared__ int lastf;
    int tid = threadIdx.x;
    int p0  = blockIdx.x * 16;

    float vals[16];
    float m = -1e30f;
#pragma unroll
    for (int i = 0; i < 16; ++i) {
        vals[i] = logits[i * 256 + tid];
        m = fmaxf(m, vals[i]);
    }
    red[tid] = m; __syncthreads();
    for (int s = 128; s > 0; s >>= 1) {
        if (tid < s) red[tid] = fmaxf(red[tid], red[tid + s]);
        __syncthreads();
    }
    m = red[0]; __syncthreads();
    float sum = 0.0f;
#pragma unroll
    for (int i = 0; i < 16; ++i) sum += __expf(vals[i] - m);
    red[tid] = sum; __syncthreads();
    for (int s = 128; s > 0; s >>= 1) {
        if (tid < s) red[tid] += red[tid + s];
        __syncthreads();
    }
    if (tid == 0) red[0] = 1.0f / red[0];
    __syncthreads();
    float invZ = red[0];
    if (tid < 16) wts[tid] = __expf(logits[p0 + tid] - m) * invZ;
    __syncthreads();

    float acc = 0.0f;
#pragma unroll
    for (int j = 0; j < 16; ++j)
        acc += wts[j] * bf2f(h_final[(size_t)(p0 + j) * HID + tid]);
    atomicAdd(&path_emb[tid], acc);

    // release: every thread's add made visible, then whole block synced,
    // THEN the ticket increments.
    __threadfence();
    __syncthreads();
    if (tid == 0) {
        unsigned int old = atomicAdd(done, 1u);
        lastf = (old == 255u) ? 1 : 0;
    }
    __syncthreads();
    if (lastf) {
        __threadfence();                 // acquire all blocks' partials
        float pe = __hip_atomic_load(&path_emb[tid], __ATOMIC_RELAXED,
                                     __HIP_MEMORY_SCOPE_AGENT);
        int u  = user_id[0];
        int it = item_id[0];
        float s = w_lin[tid]       * embedding[(size_t)u  * DIM + tid]
                + w_lin[256 + tid] * embedding[(size_t)it * DIM + tid]
                + w_lin[512 + tid] * pe;
        red[tid] = s; __syncthreads();
        for (int st = 128; st > 0; st >>= 1) {
            if (tid < st) red[tid] += red[tid + st];
            __syncthreads();
        }
        if (tid == 0) out[0] = 1.0f / (1.0f + __expf(-(red[0] + b_lin[0])));
    }
}

// ---------------------------------------------------------------------------
extern "C" void kernel_launch(void* const* d_in, const int* in_sizes, int n_in,
                              void* d_out, int out_size, void* d_ws, size_t ws_size,
                              hipStream_t stream) {
    const float* embedding = (const float*)d_in[0];
    const float* w_ih      = (const float*)d_in[1];
    const float* w_hh      = (const float*)d_in[2];
    const float* b_ih      = (const float*)d_in[3];
    const float* b_hh      = (const float*)d_in[4];
    const float* w_lin     = (const float*)d_in[5];
    const float* b_lin     = (const float*)d_in[6];
    const int*   paths     = (const int*)d_in[7];
    const int*   user_id   = (const int*)d_in[8];
    const int*   item_id   = (const int*)d_in[9];
    float* outp = (float*)d_out;

    // workspace layout (~3.1 MB), 256-B aligned
    char* ws = (char*)d_ws;
    size_t off = 0;
    auto alloc = [&](size_t n) { void* p = ws + off; off = (off + n + 255) & ~(size_t)255; return p; };
    unsigned short* WfB      = (unsigned short*)alloc((size_t)1024 * 512 * 2);   // 1 MB
    float*          bias     = (float*)alloc(1024 * 4);                          // 4 KB
    float*          path_emb = (float*)alloc(HID * 4);                           // 1 KB
    float*          logits   = (float*)alloc(NPATHS * 4);                        // 16 KB
    unsigned short* h_final  = (unsigned short*)alloc((size_t)NPATHS * HID * 2); // 2 MB
    unsigned int*   done     = (unsigned int*)alloc(4);

    prep_kernel<<<512, 256, 0, stream>>>(w_ih, w_hh, b_ih, b_hh, WfB, bias,
                                         path_emb, done);

    mega_kernel<<<256, 1024, 0, stream>>>(embedding, paths, WfB, bias,
                                          h_final, logits);

    attn_final_kernel<<<256, 256, 0, stream>>>(h_final, logits, path_emb, done,
                                               embedding, user_id, item_id,
                                               w_lin, b_lin, outp);
}

// Round 6
// 409.191 us; speedup vs baseline: 1.2939x; 1.0425x over previous
//
#include <hip/hip_runtime.h>
#include <stdint.h>

#define NPATHS 4096
#define LPATH  8
#define DIM    256
#define HID    256

typedef short  short4v __attribute__((ext_vector_type(4)));
typedef short  short8v __attribute__((ext_vector_type(8)));
typedef float  float4v __attribute__((ext_vector_type(4)));

__device__ __forceinline__ unsigned short f2bf(float f) {
    union { float f; uint32_t u; } v; v.f = f;
    uint32_t u = v.u;
    u += 0x7FFFu + ((u >> 16) & 1u);   // round-to-nearest-even
    return (unsigned short)(u >> 16);
}
__device__ __forceinline__ float bf2f(unsigned short s) {
    return __uint_as_float(((uint32_t)s) << 16);
}
__device__ __forceinline__ float fast_sigmoid(float x) {
    return 1.0f / (1.0f + __expf(-x));
}
__device__ __forceinline__ float fast_tanh(float x) {
    x = fminf(15.0f, fmaxf(-15.0f, x));
    float e = __expf(2.0f * x);
    return (e - 1.0f) / (e + 1.0f);
}

// ---------------------------------------------------------------------------
// K0: pack weights into B-fragment order + bias + zero path_emb/done.
// WfB (shorts): [(g*16+kc)][unit][quad*8+j] -> step wave load is coalesced.
// ---------------------------------------------------------------------------
__global__ void prep_kernel(const float* __restrict__ w_ih, const float* __restrict__ w_hh,
                            const float* __restrict__ b_ih, const float* __restrict__ b_hh,
                            unsigned short* __restrict__ WfB, float* __restrict__ bias,
                            float* __restrict__ path_emb, unsigned int* __restrict__ done) {
    int gid  = blockIdx.x * 256 + threadIdx.x;    // 0..131071
    int base = gid * 4;                           // short index, %4==0
    int j0   = base & 31;                         // quad*8+j
    int unit = (base >> 5) & 255;
    int gkc  = base >> 13;                        // g*16+kc, 0..63
    int g    = gkc >> 4, kc = gkc & 15;
    int row  = g * 256 + unit;
    int k    = kc * 32 + j0;
    const float* src = (k < DIM) ? (w_ih + (size_t)row * DIM + k)
                                 : (w_hh + (size_t)row * HID + (k - DIM));
    float4 v = *(const float4*)src;
    short4v pk = {(short)f2bf(v.x), (short)f2bf(v.y), (short)f2bf(v.z), (short)f2bf(v.w)};
    *(short4v*)(WfB + base) = pk;
    if (gid < 1024) bias[gid] = b_ih[gid] + b_hh[gid];
    if (gid < 256)  path_emb[gid] = 0.0f;
    if (gid == 0)   *done = 0u;
}

// ---------------------------------------------------------------------------
// K1 (mega): ALL 8 LSTM steps in one kernel. 256 blocks x 1024 threads.
//
// REGISTER-BUDGET LESSON (R3-R5 counters): for a 1024-thread block the 2nd
// __launch_bounds__ arg is clamped/ignored ((1024,4) and (1024,1) produced
// bit-identical binaries: VGPR=64, 554 MB scratch fetch, 140 MB write,
// 288 us -- dur == hbm_bytes/BW, i.e. spill-bound). The allocator's
// occupancy heuristic picks 8 waves/SIMD (64 VGPR) and spills ~25 regs in
// the kc loop. Fix: pin occupancy with amdgpu_waves_per_eu(4,4) -- a
// 16-wave block at 1 block/CU IS 4 waves/SIMD -- giving the allocator a
// 512/4 = 128 VGPR budget. Demand is ~85, so spills disappear.
//
// Block owns 16 paths x all 256 units -> recurrence is block-local:
//   h: 8 KB XOR-swizzled LDS (bf16), c: registers (4 f32/lane).
//   x: gathered inline one step ahead via NONTEMPORAL loads.
//   B: streamed from L2 every step (1 MB/block/step; 2 GB chip-wide over
//      the kernel at ~34.5 TB/s aggregate L2 ~ 58 us expected floor).
// Wave w owns unit-frag w (units 16w..16w+15), all 4 gates: per kc 4 MFMAs,
// B ring 2-deep = 32 VGPR, prologue at t-loop top so Bs is dead across the
// pointwise/store tail (liveness trim). i,f,g,o of one (path,unit) land in
// the same lane -> register pointwise, c never leaves registers.
// 2 barriers per step. At t=7: per-path max -> logits, h -> h_final.
// ---------------------------------------------------------------------------
__global__ __launch_bounds__(1024)
__attribute__((amdgpu_waves_per_eu(4, 4)))
void mega_kernel(const float* __restrict__ embedding, const int* __restrict__ paths,
                 const unsigned short* __restrict__ WfB, const float* __restrict__ bias,
                 unsigned short* __restrict__ h_final, float* __restrict__ logits) {
    __shared__ __align__(16) short sAx[2][8 * 512];   // x A-frags, double-buffered (16 KB)
    __shared__ __align__(16) short h_lds[16 * 256];   // h (bf16), XOR-swizzled (8 KB)
    __shared__ float red[16 * 16];                    // per-wave row-max partials

    const int tid  = threadIdx.x;
    const int w    = tid >> 6;        // 0..15
    const int lane = tid & 63;
    const int l15  = lane & 15;
    const int quad = lane >> 4;
    const int p0   = blockIdx.x * 16;
    const int unit = w * 16 + l15;    // this wave's unit-frag
    const unsigned short* wbase = WfB + unit * 32 + quad * 8;

    float bb[4];
#pragma unroll
    for (int g = 0; g < 4; ++g) bb[g] = bias[g * 256 + unit];

    // gather x(0): 4 floats/thread -> one b64 LDS write (fragment order)
    const int grow = tid & 15;            // path row
    const int gk0  = (tid >> 4) * 4;      // k offset 0..252
    const int gdst = (gk0 >> 5) * 512 + (((gk0 >> 3) & 3) * 16 + grow) * 8 + (gk0 & 4);
    {
        int node = paths[(p0 + grow) * LPATH];
        float4v v = __builtin_nontemporal_load(
            (const float4v*)(embedding + (size_t)node * DIM + gk0));
        short4v pk = {(short)f2bf(v[0]), (short)f2bf(v[1]),
                      (short)f2bf(v[2]), (short)f2bf(v[3])};
        *(short4v*)(&sAx[0][gdst]) = pk;
    }

    float cc[4] = {0.0f, 0.0f, 0.0f, 0.0f};

    short8v Bs[2][4];                     // 2-deep kc ring, 32 VGPR
    auto loadBk = [&](int kc, int slot) {
#pragma unroll
        for (int g = 0; g < 4; ++g)
            Bs[slot][g] = *(const short8v*)(wbase + (size_t)(g * 16 + kc) * 8192);
    };

    __syncthreads();                      // x(0) staged

#pragma unroll 1
    for (int t = 0; t < LPATH; ++t) {
        const bool first = (t == 0), last = (t == LPATH - 1);

        loadBk(0, 0); loadBk(1, 1);       // ring prologue (Bs dead until here)

        // issue gather of x(t+1) early (nontemporal; consumed after kc loop)
        float4v gv;
        if (!last) {
            int node = paths[(p0 + grow) * LPATH + t + 1];
            gv = __builtin_nontemporal_load(
                (const float4v*)(embedding + (size_t)node * DIM + gk0));
        }

        float4v acc[4];
        const float4v z4 = {0.0f, 0.0f, 0.0f, 0.0f};
#pragma unroll
        for (int g = 0; g < 4; ++g) acc[g] = z4;

        const short* sacur = sAx[t & 1];

        auto kstep = [&](int kc, short8v a) {
#pragma unroll
            for (int g = 0; g < 4; ++g)
                acc[g] = __builtin_amdgcn_mfma_f32_16x16x32_bf16(
                    a, Bs[kc & 1][g], acc[g], 0, 0, 0);
        };

        if (first) {
#pragma unroll
            for (int kc = 0; kc < 8; ++kc) {          // h==0: x-half only
                short8v a = *(const short8v*)(sacur + kc * 512 + lane * 8);
                kstep(kc, a);
                if (kc + 2 < 8) loadBk(kc + 2, kc & 1);
            }
        } else {
#pragma unroll
            for (int kc = 0; kc < 16; ++kc) {
                short8v a;
                if (kc < 8) {
                    a = *(const short8v*)(sacur + kc * 512 + lane * 8);
                } else {
                    int cg  = (kc - 8) * 4 + quad;    // 16-B group of h row
                    int cgs = cg ^ (l15 & 7);         // XOR swizzle (bank-spread)
                    a = *(const short8v*)(&h_lds[l15 * 256 + cgs * 8]);
                }
                kstep(kc, a);
                if (kc + 2 < 16) loadBk(kc + 2, kc & 1);
            }
        }

        // stage sAx[next] (that buffer's reads finished a full step ago)
        if (!last) {
            short4v pk = {(short)f2bf(gv[0]), (short)f2bf(gv[1]),
                          (short)f2bf(gv[2]), (short)f2bf(gv[3])};
            *(short4v*)(&sAx[(t + 1) & 1][gdst]) = pk;
        }

        // pointwise LSTM update: 4 cells/lane, c persistent in registers
        float hv[4];
#pragma unroll
        for (int r = 0; r < 4; ++r) {
            float iv = acc[0][r] + bb[0];
            float fv = acc[1][r] + bb[1];
            float gg = acc[2][r] + bb[2];
            float ov = acc[3][r] + bb[3];
            float cn = fast_sigmoid(fv) * cc[r] + fast_sigmoid(iv) * fast_tanh(gg);
            cc[r] = cn;
            hv[r] = fast_sigmoid(ov) * fast_tanh(cn);
        }

        __syncthreads();   // barrier B: all reads of h_lds / sAx[cur] done

        // write new h into h_lds (same XOR swizzle as the read side)
#pragma unroll
        for (int r = 0; r < 4; ++r) {
            int pr  = quad * 4 + r;
            int cgs = (unit >> 3) ^ (pr & 7);
            h_lds[pr * 256 + cgs * 8 + (unit & 7)] = (short)f2bf(hv[r]);
        }

        if (last) {
            // per-path max over this wave's 16 units -> LDS partials
#pragma unroll
            for (int r = 0; r < 4; ++r) {
                float m = hv[r];
                m = fmaxf(m, __shfl_xor(m, 1, 64));
                m = fmaxf(m, __shfl_xor(m, 2, 64));
                m = fmaxf(m, __shfl_xor(m, 4, 64));
                m = fmaxf(m, __shfl_xor(m, 8, 64));
                if (l15 == 0) red[(quad * 4 + r) * 16 + w] = m;
            }
        }
        __syncthreads();   // barrier A': h_lds (and red) visible
    }

    // logits: block-owned paths -> plain stores, no atomics
    if (tid < 16) {
        float m = red[tid * 16];
#pragma unroll
        for (int j = 1; j < 16; ++j) m = fmaxf(m, red[tid * 16 + j]);
        logits[p0 + tid] = m;
    }
    // h_final writeback, coalesced: de-swizzle (group i5 of row lives at
    // swizzled slot cgs = i5 ^ (row&7); store it at its TRUE offset i5*8).
    if (tid < 512) {
        int row = tid >> 5, i5 = tid & 31;
        int cgs = i5 ^ (row & 7);
        short8v v = *(const short8v*)(&h_lds[row * 256 + cgs * 8]);
        *(short8v*)(h_final + (size_t)(p0 + row) * HID + (size_t)i5 * 8) = v;
    }
}

// ---------------------------------------------------------------------------
// K2: fused softmax + attention + (last block) final linear+sigmoid.
// 256 blocks x 256 threads; each block redundantly computes the global
// softmax scalars from the 16 KB logits array, accumulates its 16 paths
// into path_emb, then the LAST block (device-scope ticket, properly
// fenced+barriered) computes out.
// ---------------------------------------------------------------------------
__global__ void attn_final_kernel(const unsigned short* __restrict__ h_final,
                                  const float* __restrict__ logits,
                                  float* __restrict__ path_emb,
                                  unsigned int* __restrict__ done,
                                  const float* __restrict__ embedding,
                                  const int* __restrict__ user_id,
                                  const int* __restrict__ item_id,
                                  const float* __restrict__ w_lin,
                                  const float* __restrict__ b_lin,
                                  float* __restrict__ out) {
    __shared__ float red[256];
    __shared__ float wts[16];
    __shared__ int lastf;
    int tid = threadIdx.x;
    int p0  = blockIdx.x * 16;

    float vals[16];
    float m = -1e30f;
#pragma unroll
    for (int i = 0; i < 16; ++i) {
        vals[i] = logits[i * 256 + tid];
        m = fmaxf(m, vals[i]);
    }
    red[tid] = m; __syncthreads();
    for (int s = 128; s > 0; s >>= 1) {
        if (tid < s) red[tid] = fmaxf(red[tid], red[tid + s]);
        __syncthreads();
    }
    m = red[0]; __syncthreads();
    float sum = 0.0f;
#pragma unroll
    for (int i = 0; i < 16; ++i) sum += __expf(vals[i] - m);
    red[tid] = sum; __syncthreads();
    for (int s = 128; s > 0; s >>= 1) {
        if (tid < s) red[tid] += red[tid + s];
        __syncthreads();
    }
    if (tid == 0) red[0] = 1.0f / red[0];
    __syncthreads();
    float invZ = red[0];
    if (tid < 16) wts[tid] = __expf(logits[p0 + tid] - m) * invZ;
    __syncthreads();

    float acc = 0.0f;
#pragma unroll
    for (int j = 0; j < 16; ++j)
        acc += wts[j] * bf2f(h_final[(size_t)(p0 + j) * HID + tid]);
    atomicAdd(&path_emb[tid], acc);

    // release: every thread's add made visible, then whole block synced,
    // THEN the ticket increments.
    __threadfence();
    __syncthreads();
    if (tid == 0) {
        unsigned int old = atomicAdd(done, 1u);
        lastf = (old == 255u) ? 1 : 0;
    }
    __syncthreads();
    if (lastf) {
        __threadfence();                 // acquire all blocks' partials
        float pe = __hip_atomic_load(&path_emb[tid], __ATOMIC_RELAXED,
                                     __HIP_MEMORY_SCOPE_AGENT);
        int u  = user_id[0];
        int it = item_id[0];
        float s = w_lin[tid]       * embedding[(size_t)u  * DIM + tid]
                + w_lin[256 + tid] * embedding[(size_t)it * DIM + tid]
                + w_lin[512 + tid] * pe;
        red[tid] = s; __syncthreads();
        for (int st = 128; st > 0; st >>= 1) {
            if (tid < st) red[tid] += red[tid + st];
            __syncthreads();
        }
        if (tid == 0) out[0] = 1.0f / (1.0f + __expf(-(red[0] + b_lin[0])));
    }
}

// ---------------------------------------------------------------------------
extern "C" void kernel_launch(void* const* d_in, const int* in_sizes, int n_in,
                              void* d_out, int out_size, void* d_ws, size_t ws_size,
                              hipStream_t stream) {
    const float* embedding = (const float*)d_in[0];
    const float* w_ih      = (const float*)d_in[1];
    const float* w_hh      = (const float*)d_in[2];
    const float* b_ih      = (const float*)d_in[3];
    const float* b_hh      = (const float*)d_in[4];
    const float* w_lin     = (const float*)d_in[5];
    const float* b_lin     = (const float*)d_in[6];
    const int*   paths     = (const int*)d_in[7];
    const int*   user_id   = (const int*)d_in[8];
    const int*   item_id   = (const int*)d_in[9];
    float* outp = (float*)d_out;

    // workspace layout (~3.1 MB), 256-B aligned
    char* ws = (char*)d_ws;
    size_t off = 0;
    auto alloc = [&](size_t n) { void* p = ws + off; off = (off + n + 255) & ~(size_t)255; return p; };
    unsigned short* WfB      = (unsigned short*)alloc((size_t)1024 * 512 * 2);   // 1 MB
    float*          bias     = (float*)alloc(1024 * 4);                          // 4 KB
    float*          path_emb = (float*)alloc(HID * 4);                           // 1 KB
    float*          logits   = (float*)alloc(NPATHS * 4);                        // 16 KB
    unsigned short* h_final  = (unsigned short*)alloc((size_t)NPATHS * HID * 2); // 2 MB
    unsigned int*   done     = (unsigned int*)alloc(4);

    prep_kernel<<<512, 256, 0, stream>>>(w_ih, w_hh, b_ih, b_hh, WfB, bias,
                                         path_emb, done);

    mega_kernel<<<256, 1024, 0, stream>>>(embedding, paths, WfB, bias,
                                          h_final, logits);

    attn_final_kernel<<<256, 256, 0, stream>>>(h_final, logits, path_emb, done,
                                               embedding, user_id, item_id,
                                               w_lin, b_lin, outp);
}

// Round 8
// 280.627 us; speedup vs baseline: 1.8867x; 1.4581x over previous
//
#include <hip/hip_runtime.h>
#include <stdint.h>

#define NPATHS 4096
#define LPATH  8
#define DIM    256
#define HID    256

typedef short  short4v __attribute__((ext_vector_type(4)));
typedef short  short8v __attribute__((ext_vector_type(8)));
typedef float  float4v __attribute__((ext_vector_type(4)));

__device__ __forceinline__ unsigned short f2bf(float f) {
    union { float f; uint32_t u; } v; v.f = f;
    uint32_t u = v.u;
    u += 0x7FFFu + ((u >> 16) & 1u);   // round-to-nearest-even
    return (unsigned short)(u >> 16);
}
__device__ __forceinline__ float bf2f(unsigned short s) {
    return __uint_as_float(((uint32_t)s) << 16);
}
__device__ __forceinline__ float fast_sigmoid(float x) {
    return 1.0f / (1.0f + __expf(-x));
}
__device__ __forceinline__ float fast_tanh(float x) {
    x = fminf(15.0f, fmaxf(-15.0f, x));
    float e = __expf(2.0f * x);
    return (e - 1.0f) / (e + 1.0f);
}

// async global->LDS DMA, 16 B/lane (global_load_lds_dwordx4).
// Global address is per-lane; LDS dest is wave-uniform base + lane*16.
__device__ __forceinline__ void dma16(void* lds, const void* g) {
    typedef const unsigned int __attribute__((address_space(1)))* gp_t;
    typedef unsigned int __attribute__((address_space(3)))* lp_t;
    gp_t gp = reinterpret_cast<gp_t>(reinterpret_cast<uintptr_t>(g));
    lp_t lp = reinterpret_cast<lp_t>(static_cast<unsigned int>(reinterpret_cast<uintptr_t>(lds)));
    __builtin_amdgcn_global_load_lds(gp, lp, 16, 0, 0);
}

// ---------------------------------------------------------------------------
// K0: pack weights into B-fragment order + bias + zero path_emb/done.
// WfB layout (shorts): [(g*16+kc)][quad][unit][8]
//   -> the per-kc 64 KB slice is 4x 16 KB contiguous gate-chunks (linear DMA),
//      and the per-lane ds_read (unit = w*16+l15 in the low dims) is
//      quarter-wave-contiguous (canonical conflict-free b128 pattern).
// Fragment CONTENTS per (g,kc,unit,quad,j) identical to the proven R5 kernel:
//   element k = kc*32 + quad*8 + j of row g*256+unit.
// ---------------------------------------------------------------------------
__global__ void prep_kernel(const float* __restrict__ w_ih, const float* __restrict__ w_hh,
                            const float* __restrict__ b_ih, const float* __restrict__ b_hh,
                            unsigned short* __restrict__ WfB, float* __restrict__ bias,
                            float* __restrict__ path_emb, unsigned int* __restrict__ done) {
    int gid  = blockIdx.x * 256 + threadIdx.x;    // 0..131071
    int base = gid * 4;                           // short index, %4==0
    int j0   = base & 7;                          // 0 or 4
    int unit = (base >> 3) & 255;
    int quad = (base >> 11) & 3;
    int gkc  = base >> 13;                        // g*16+kc, 0..63
    int g    = gkc >> 4, kc = gkc & 15;
    int row  = g * 256 + unit;
    int k    = kc * 32 + quad * 8 + j0;
    const float* src = (k < DIM) ? (w_ih + (size_t)row * DIM + k)
                                 : (w_hh + (size_t)row * HID + (k - DIM));
    float4 v = *(const float4*)src;
    short4v pk = {(short)f2bf(v.x), (short)f2bf(v.y), (short)f2bf(v.z), (short)f2bf(v.w)};
    *(short4v*)(WfB + base) = pk;
    if (gid < 1024) bias[gid] = b_ih[gid] + b_hh[gid];
    if (gid < 256)  path_emb[gid] = 0.0f;
    if (gid == 0)   *done = 0u;
}

// ---------------------------------------------------------------------------
// K1 (mega): ALL 8 LSTM steps in one kernel. 256 blocks x 1024 threads.
//
// SPILL LESSON (R3-R6 counters): for 1024-thread blocks the allocator pins
// VGPR=64 regardless of __launch_bounds__ 2nd arg / waves_per_eu hints; any
// per-lane state beyond ~60 regs becomes in-loop scratch traffic (R6: 357 MB
// fetch + 91 MB write = spill-bound at 257 us). Fix is structural, not
// attribute-based: the 32-VGPR B register ring is replaced by LDS staging
// via global_load_lds DMA (ZERO VGPR cost) + one transient ds_read_b128 per
// gate feeding its MFMA. Register demand drops to ~55 -> fits 64, no spill.
//
// B pipeline: per kc the block needs 64 KB of WfB (4 gates x 256 units x
// 32 B). Two 64-KB LDS slots double-buffer the kc stream; each kc body
// issues the DMA for kc+1 into the other slot (wave w stages quarter w&3 of
// gate w>>2 = 4x dma16), ds_reads + 4 MFMAs consume the current slot, and
// __syncthreads() (full vmcnt drain) fences the DMA. 64 KB of 1-KB requests
// in flight per block saturates the per-CU L2 port; B is t-invariant so the
// kc stream runs seamlessly across steps (t=7 kc15 stages nothing).
//
// Block owns 16 paths x all 256 units -> recurrence block-local:
//   h: 8 KB XOR-swizzled LDS (bf16), c: registers (4 f32/lane),
//   x: gathered inline one step ahead (nontemporal), staged into sAx at the
//      step tail (single buffer: reads at kc 0..7, write 8+ barriers later).
// LDS: 128 KB sB + 8 KB sAx + 8 KB h_lds + 1 KB red = 148.5 KB (<160 KB CU).
// At t=7: per-path max -> logits (block-owned), h -> h_final (de-swizzled).
//
// Hang audit (R7 container failure was infra): all barriers are executed
// under block-uniform conditions; every DMA batch is fenced by the same
// iteration's barrier; no spin-waits anywhere.
// ---------------------------------------------------------------------------
__global__ __launch_bounds__(1024)
__attribute__((amdgpu_waves_per_eu(4, 4)))
void mega_kernel(const float* __restrict__ embedding, const int* __restrict__ paths,
                 const unsigned short* __restrict__ WfB, const float* __restrict__ bias,
                 unsigned short* __restrict__ h_final, float* __restrict__ logits) {
    __shared__ __align__(16) short sB[2][32768];      // B kc-slices, dbuf (128 KB)
    __shared__ __align__(16) short sAx[8 * 512];      // x A-frags (8 KB)
    __shared__ __align__(16) short h_lds[16 * 256];   // h (bf16), XOR-swizzled (8 KB)
    __shared__ float red[16 * 16];                    // per-wave row-max partials

    const int tid  = threadIdx.x;
    const int w    = tid >> 6;        // 0..15
    const int lane = tid & 63;
    const int l15  = lane & 15;
    const int quad = lane >> 4;
    const int p0   = blockIdx.x * 16;
    const int unit = w * 16 + l15;    // this wave's unit-frag

    // staging role: wave w stages quarter (w&3) of gate (w>>2)
    const int sg = w >> 2;
    const int sq = w & 3;
    const short* WfB_s = (const short*)WfB;

    auto stageB = [&](int kc, int slot) {
        const short* gsrc = WfB_s + (size_t)(sg * 16 + kc) * 8192 + sq * 2048 + lane * 8;
        short* ldst = &sB[slot][sg * 8192 + sq * 2048];
#pragma unroll
        for (int i = 0; i < 4; ++i)
            dma16(ldst + i * 512, gsrc + i * 512);
    };

    float bb[4];
#pragma unroll
    for (int g = 0; g < 4; ++g) bb[g] = bias[g * 256 + unit];

    // gather x(0): 4 floats/thread -> one b64 LDS write (fragment order)
    const int grow = tid & 15;            // path row
    const int gk0  = (tid >> 4) * 4;      // k offset 0..252
    const int gdst = (gk0 >> 5) * 512 + (((gk0 >> 3) & 3) * 16 + grow) * 8 + (gk0 & 4);
    {
        int node = paths[(p0 + grow) * LPATH];
        float4v v = __builtin_nontemporal_load(
            (const float4v*)(embedding + (size_t)node * DIM + gk0));
        short4v pk = {(short)f2bf(v[0]), (short)f2bf(v[1]),
                      (short)f2bf(v[2]), (short)f2bf(v[3])};
        *(short4v*)(&sAx[gdst]) = pk;
    }

    float cc[4] = {0.0f, 0.0f, 0.0f, 0.0f};

    stageB(0, 0);                         // prologue: kc=0 into slot 0
    int cur = 0;
    __syncthreads();                      // drains DMA(0) + x(0) LDS write

#pragma unroll 1
    for (int t = 0; t < LPATH; ++t) {
        const bool first = (t == 0), last = (t == LPATH - 1);
        const int  K     = first ? 8 : 16;

        // issue gather of x(t+1) early (nontemporal; consumed at step tail)
        float4v gv;
        if (!last) {
            int node = paths[(p0 + grow) * LPATH + t + 1];
            gv = __builtin_nontemporal_load(
                (const float4v*)(embedding + (size_t)node * DIM + gk0));
        }

        float4v acc[4];
        const float4v z4 = {0.0f, 0.0f, 0.0f, 0.0f};
#pragma unroll
        for (int g = 0; g < 4; ++g) acc[g] = z4;

#pragma unroll 1
        for (int kc = 0; kc < K; ++kc) {
            int nxt = cur ^ 1;
            // stage next kc of the global stream (wraps to 0 for next step)
            if (!(last && kc == K - 1))
                stageB((kc + 1 < K) ? kc + 1 : 0, nxt);

            // A fragment
            short8v a;
            if (kc < 8) {
                a = *(const short8v*)(sAx + kc * 512 + lane * 8);
            } else {
                int cg  = (kc - 8) * 4 + quad;    // 16-B group of h row
                int cgs = cg ^ (l15 & 7);         // XOR swizzle (bank-spread)
                a = *(const short8v*)(&h_lds[l15 * 256 + cgs * 8]);
            }
            // B fragments (transient: ds_read -> MFMA)
#pragma unroll
            for (int g = 0; g < 4; ++g) {
                short8v bf = *(const short8v*)(&sB[cur][g * 8192 + quad * 2048 + unit * 8]);
                acc[g] = __builtin_amdgcn_mfma_f32_16x16x32_bf16(a, bf, acc[g], 0, 0, 0);
            }

            __syncthreads();   // fences DMA(nxt) + this kc's ds_reads
            cur = nxt;
        }

        // stage sAx for next step (reads of sAx ended >=8 barriers ago)
        if (!last) {
            short4v pk = {(short)f2bf(gv[0]), (short)f2bf(gv[1]),
                          (short)f2bf(gv[2]), (short)f2bf(gv[3])};
            *(short4v*)(&sAx[gdst]) = pk;
        }

        // pointwise LSTM update: 4 cells/lane, c persistent in registers
        float hv[4];
#pragma unroll
        for (int r = 0; r < 4; ++r) {
            float iv = acc[0][r] + bb[0];
            float fv = acc[1][r] + bb[1];
            float gg = acc[2][r] + bb[2];
            float ov = acc[3][r] + bb[3];
            float cn = fast_sigmoid(fv) * cc[r] + fast_sigmoid(iv) * fast_tanh(gg);
            cc[r] = cn;
            hv[r] = fast_sigmoid(ov) * fast_tanh(cn);
        }

        // write new h into h_lds (same XOR swizzle as the read side).
        // Safe: last kc barrier ordered all h_lds reads before this point.
#pragma unroll
        for (int r = 0; r < 4; ++r) {
            int pr  = quad * 4 + r;
            int cgs = (unit >> 3) ^ (pr & 7);
            h_lds[pr * 256 + cgs * 8 + (unit & 7)] = (short)f2bf(hv[r]);
        }

        if (last) {
            // per-path max over this wave's 16 units -> LDS partials
#pragma unroll
            for (int r = 0; r < 4; ++r) {
                float m = hv[r];
                m = fmaxf(m, __shfl_xor(m, 1, 64));
                m = fmaxf(m, __shfl_xor(m, 2, 64));
                m = fmaxf(m, __shfl_xor(m, 4, 64));
                m = fmaxf(m, __shfl_xor(m, 8, 64));
                if (l15 == 0) red[(quad * 4 + r) * 16 + w] = m;
            }
        }
        __syncthreads();   // h_lds (+ red / sAx) visible for next step
    }

    // logits: block-owned paths -> plain stores, no atomics
    if (tid < 16) {
        float m = red[tid * 16];
#pragma unroll
        for (int j = 1; j < 16; ++j) m = fmaxf(m, red[tid * 16 + j]);
        logits[p0 + tid] = m;
    }
    // h_final writeback, coalesced: de-swizzle (group i5 of row lives at
    // swizzled slot cgs = i5 ^ (row&7); store it at its TRUE offset i5*8).
    if (tid < 512) {
        int row = tid >> 5, i5 = tid & 31;
        int cgs = i5 ^ (row & 7);
        short8v v = *(const short8v*)(&h_lds[row * 256 + cgs * 8]);
        *(short8v*)(h_final + (size_t)(p0 + row) * HID + (size_t)i5 * 8) = v;
    }
}

// ---------------------------------------------------------------------------
// K2: fused softmax + attention + (last block) final linear+sigmoid.
// 256 blocks x 256 threads; each block redundantly computes the global
// softmax scalars from the 16 KB logits array, accumulates its 16 paths
// into path_emb, then the LAST block (device-scope ticket, properly
// fenced+barriered) computes out.
// ---------------------------------------------------------------------------
__global__ void attn_final_kernel(const unsigned short* __restrict__ h_final,
                                  const float* __restrict__ logits,
                                  float* __restrict__ path_emb,
                                  unsigned int* __restrict__ done,
                                  const float* __restrict__ embedding,
                                  const int* __restrict__ user_id,
                                  const int* __restrict__ item_id,
                                  const float* __restrict__ w_lin,
                                  const float* __restrict__ b_lin,
                                  float* __restrict__ out) {
    __shared__ float red[256];
    __shared__ float wts[16];
    __shared__ int lastf;
    int tid = threadIdx.x;
    int p0  = blockIdx.x * 16;

    float vals[16];
    float m = -1e30f;
#pragma unroll
    for (int i = 0; i < 16; ++i) {
        vals[i] = logits[i * 256 + tid];
        m = fmaxf(m, vals[i]);
    }
    red[tid] = m; __syncthreads();
    for (int s = 128; s > 0; s >>= 1) {
        if (tid < s) red[tid] = fmaxf(red[tid], red[tid + s]);
        __syncthreads();
    }
    m = red[0]; __syncthreads();
    float sum = 0.0f;
#pragma unroll
    for (int i = 0; i < 16; ++i) sum += __expf(vals[i] - m);
    red[tid] = sum; __syncthreads();
    for (int s = 128; s > 0; s >>= 1) {
        if (tid < s) red[tid] += red[tid + s];
        __syncthreads();
    }
    if (tid == 0) red[0] = 1.0f / red[0];
    __syncthreads();
    float invZ = red[0];
    if (tid < 16) wts[tid] = __expf(logits[p0 + tid] - m) * invZ;
    __syncthreads();

    float acc = 0.0f;
#pragma unroll
    for (int j = 0; j < 16; ++j)
        acc += wts[j] * bf2f(h_final[(size_t)(p0 + j) * HID + tid]);
    atomicAdd(&path_emb[tid], acc);

    // release: every thread's add made visible, then whole block synced,
    // THEN the ticket increments.
    __threadfence();
    __syncthreads();
    if (tid == 0) {
        unsigned int old = atomicAdd(done, 1u);
        lastf = (old == 255u) ? 1 : 0;
    }
    __syncthreads();
    if (lastf) {
        __threadfence();                 // acquire all blocks' partials
        float pe = __hip_atomic_load(&path_emb[tid], __ATOMIC_RELAXED,
                                     __HIP_MEMORY_SCOPE_AGENT);
        int u  = user_id[0];
        int it = item_id[0];
        float s = w_lin[tid]       * embedding[(size_t)u  * DIM + tid]
                + w_lin[256 + tid] * embedding[(size_t)it * DIM + tid]
                + w_lin[512 + tid] * pe;
        red[tid] = s; __syncthreads();
        for (int st = 128; st > 0; st >>= 1) {
            if (tid < st) red[tid] += red[tid + st];
            __syncthreads();
        }
        if (tid == 0) out[0] = 1.0f / (1.0f + __expf(-(red[0] + b_lin[0])));
    }
}

// ---------------------------------------------------------------------------
extern "C" void kernel_launch(void* const* d_in, const int* in_sizes, int n_in,
                              void* d_out, int out_size, void* d_ws, size_t ws_size,
                              hipStream_t stream) {
    const float* embedding = (const float*)d_in[0];
    const float* w_ih      = (const float*)d_in[1];
    const float* w_hh      = (const float*)d_in[2];
    const float* b_ih      = (const float*)d_in[3];
    const float* b_hh      = (const float*)d_in[4];
    const float* w_lin     = (const float*)d_in[5];
    const float* b_lin     = (const float*)d_in[6];
    const int*   paths     = (const int*)d_in[7];
    const int*   user_id   = (const int*)d_in[8];
    const int*   item_id   = (const int*)d_in[9];
    float* outp = (float*)d_out;

    // workspace layout (~3.1 MB), 256-B aligned
    char* ws = (char*)d_ws;
    size_t off = 0;
    auto alloc = [&](size_t n) { void* p = ws + off; off = (off + n + 255) & ~(size_t)255; return p; };
    unsigned short* WfB      = (unsigned short*)alloc((size_t)1024 * 512 * 2);   // 1 MB
    float*          bias     = (float*)alloc(1024 * 4);                          // 4 KB
    float*          path_emb = (float*)alloc(HID * 4);                           // 1 KB
    float*          logits   = (float*)alloc(NPATHS * 4);                        // 16 KB
    unsigned short* h_final  = (unsigned short*)alloc((size_t)NPATHS * HID * 2); // 2 MB
    unsigned int*   done     = (unsigned int*)alloc(4);

    prep_kernel<<<512, 256, 0, stream>>>(w_ih, w_hh, b_ih, b_hh, WfB, bias,
                                         path_emb, done);

    mega_kernel<<<256, 1024, 0, stream>>>(embedding, paths, WfB, bias,
                                          h_final, logits);

    attn_final_kernel<<<256, 256, 0, stream>>>(h_final, logits, path_emb, done,
                                               embedding, user_id, item_id,
                                               w_lin, b_lin, outp);
}

// Round 9
// 277.958 us; speedup vs baseline: 1.9048x; 1.0096x over previous
//
#include <hip/hip_runtime.h>
#include <stdint.h>

#define NPATHS 4096
#define LPATH  8
#define DIM    256
#define HID    256

typedef short  short4v __attribute__((ext_vector_type(4)));
typedef short  short8v __attribute__((ext_vector_type(8)));
typedef float  float4v __attribute__((ext_vector_type(4)));

__device__ __forceinline__ unsigned short f2bf(float f) {
    union { float f; uint32_t u; } v; v.f = f;
    uint32_t u = v.u;
    u += 0x7FFFu + ((u >> 16) & 1u);   // round-to-nearest-even
    return (unsigned short)(u >> 16);
}
__device__ __forceinline__ float bf2f(unsigned short s) {
    return __uint_as_float(((uint32_t)s) << 16);
}
__device__ __forceinline__ float fast_sigmoid(float x) {
    return 1.0f / (1.0f + __expf(-x));
}
__device__ __forceinline__ float fast_tanh(float x) {
    x = fminf(15.0f, fmaxf(-15.0f, x));
    float e = __expf(2.0f * x);
    return (e - 1.0f) / (e + 1.0f);
}

// async global->LDS DMA, 16 B/lane (global_load_lds_dwordx4).
// Global address is per-lane; LDS dest is wave-uniform base + lane*16.
__device__ __forceinline__ void dma16(void* lds, const void* g) {
    typedef const unsigned int __attribute__((address_space(1)))* gp_t;
    typedef unsigned int __attribute__((address_space(3)))* lp_t;
    gp_t gp = reinterpret_cast<gp_t>(reinterpret_cast<uintptr_t>(g));
    lp_t lp = reinterpret_cast<lp_t>(static_cast<unsigned int>(reinterpret_cast<uintptr_t>(lds)));
    __builtin_amdgcn_global_load_lds(gp, lp, 16, 0, 0);
}

// ---------------------------------------------------------------------------
// K0: pack weights into B-fragment order + bias + zero path_emb/done.
// WfB layout (shorts): [(g*16+kc)][quad][unit][8]
//   -> the per-kc 64 KB slice is 4x 16 KB contiguous gate-chunks (linear DMA),
//      and the per-lane ds_read (unit = w*16+l15 in the low dims) is
//      quarter-wave-contiguous (canonical conflict-free b128 pattern).
// Fragment CONTENTS per (g,kc,unit,quad,j) identical to the proven R5 kernel:
//   element k = kc*32 + quad*8 + j of row g*256+unit.
// ---------------------------------------------------------------------------
__global__ void prep_kernel(const float* __restrict__ w_ih, const float* __restrict__ w_hh,
                            const float* __restrict__ b_ih, const float* __restrict__ b_hh,
                            unsigned short* __restrict__ WfB, float* __restrict__ bias,
                            float* __restrict__ path_emb, unsigned int* __restrict__ done) {
    int gid  = blockIdx.x * 256 + threadIdx.x;    // 0..131071
    int base = gid * 4;                           // short index, %4==0
    int j0   = base & 7;                          // 0 or 4
    int unit = (base >> 3) & 255;
    int quad = (base >> 11) & 3;
    int gkc  = base >> 13;                        // g*16+kc, 0..63
    int g    = gkc >> 4, kc = gkc & 15;
    int row  = g * 256 + unit;
    int k    = kc * 32 + quad * 8 + j0;
    const float* src = (k < DIM) ? (w_ih + (size_t)row * DIM + k)
                                 : (w_hh + (size_t)row * HID + (k - DIM));
    float4 v = *(const float4*)src;
    short4v pk = {(short)f2bf(v.x), (short)f2bf(v.y), (short)f2bf(v.z), (short)f2bf(v.w)};
    *(short4v*)(WfB + base) = pk;
    if (gid < 1024) bias[gid] = b_ih[gid] + b_hh[gid];
    if (gid < 256)  path_emb[gid] = 0.0f;
    if (gid == 0)   *done = 0u;
}

// ---------------------------------------------------------------------------
// K1 (mega): ALL 8 LSTM steps in one kernel. 256 blocks x 1024 threads.
//
// SPILL LESSON (R3-R6): 1024-thread blocks get a ~64-VGPR budget; B streams
// via global_load_lds DMA (zero VGPR) + transient ds_read_b128 per gate.
// R8 verified: VGPR=52, FETCH 20.7 MB, WRITE 2 MB -- no spill.
//
// PIPELINE LESSON (R8 -> R9): R8's per-kc schedule {issue DMA(kc+1);
// compute(kc); __syncthreads} exposed nearly the whole DMA latency+transfer
// at every barrier (vmcnt(0) drain of a DMA issued ~300 cyc earlier):
// ~2250 cyc/iter vs the 1024-cyc port bound. R9 moves the barrier to the
// TOP of the iteration: {__syncthreads [drains DMA(kc), issued a FULL
// iteration ago]; issue DMA(kc+1); compute(kc)}. Steady-state iteration ~
// max(transfer ~1150, compute+barrier ~600) cyc. Hazards: slot-nxt
// write-after-read ordered by the iter-top barrier; slot-cur
// read-after-write by each wave draining its own DMA before the barrier;
// h_lds/sAx tail writes guarded by one explicit tail barrier per step.
//
// Block owns 16 paths x all 256 units -> recurrence block-local:
//   h: 8 KB XOR-swizzled LDS (bf16), c: registers (4 f32/lane),
//   x: gathered inline one step ahead (nontemporal), issued in the kc==0
//      body so its latency hides under iter-1's DMA wait.
// LDS: 128 KB sB + 8 KB sAx + 8 KB h_lds + 1 KB red = 148.5 KB (<160 KB CU).
// At t=7: per-path max -> logits (block-owned), h -> h_final (de-swizzled).
// ---------------------------------------------------------------------------
__global__ __launch_bounds__(1024)
__attribute__((amdgpu_waves_per_eu(4, 4)))
void mega_kernel(const float* __restrict__ embedding, const int* __restrict__ paths,
                 const unsigned short* __restrict__ WfB, const float* __restrict__ bias,
                 unsigned short* __restrict__ h_final, float* __restrict__ logits) {
    __shared__ __align__(16) short sB[2][32768];      // B kc-slices, dbuf (128 KB)
    __shared__ __align__(16) short sAx[8 * 512];      // x A-frags (8 KB)
    __shared__ __align__(16) short h_lds[16 * 256];   // h (bf16), XOR-swizzled (8 KB)
    __shared__ float red[16 * 16];                    // per-wave row-max partials

    const int tid  = threadIdx.x;
    const int w    = tid >> 6;        // 0..15
    const int lane = tid & 63;
    const int l15  = lane & 15;
    const int quad = lane >> 4;
    const int p0   = blockIdx.x * 16;
    const int unit = w * 16 + l15;    // this wave's unit-frag

    // staging role: wave w stages quarter (w&3) of gate (w>>2)
    const int sg = w >> 2;
    const int sq = w & 3;
    const short* WfB_s = (const short*)WfB;

    auto stageB = [&](int kc, int slot) {
        const short* gsrc = WfB_s + (size_t)(sg * 16 + kc) * 8192 + sq * 2048 + lane * 8;
        short* ldst = &sB[slot][sg * 8192 + sq * 2048];
#pragma unroll
        for (int i = 0; i < 4; ++i)
            dma16(ldst + i * 512, gsrc + i * 512);
    };

    float bb[4];
#pragma unroll
    for (int g = 0; g < 4; ++g) bb[g] = bias[g * 256 + unit];

    // gather x(0): 4 floats/thread -> one b64 LDS write (fragment order)
    const int grow = tid & 15;            // path row
    const int gk0  = (tid >> 4) * 4;      // k offset 0..252
    const int gdst = (gk0 >> 5) * 512 + (((gk0 >> 3) & 3) * 16 + grow) * 8 + (gk0 & 4);
    {
        int node = paths[(p0 + grow) * LPATH];
        float4v v = __builtin_nontemporal_load(
            (const float4v*)(embedding + (size_t)node * DIM + gk0));
        short4v pk = {(short)f2bf(v[0]), (short)f2bf(v[1]),
                      (short)f2bf(v[2]), (short)f2bf(v[3])};
        *(short4v*)(&sAx[gdst]) = pk;
    }

    float cc[4] = {0.0f, 0.0f, 0.0f, 0.0f};

    stageB(0, 0);                         // prologue: kc=0 into slot 0
    int cur = 0;

#pragma unroll 1
    for (int t = 0; t < LPATH; ++t) {
        const bool first = (t == 0), last = (t == LPATH - 1);
        const int  K     = first ? 8 : 16;

        float4v gv;
        float4v acc[4];
        const float4v z4 = {0.0f, 0.0f, 0.0f, 0.0f};
#pragma unroll
        for (int g = 0; g < 4; ++g) acc[g] = z4;

#pragma unroll 1
        for (int kc = 0; kc < K; ++kc) {
            // Barrier FIRST: drains DMA(kc) (issued one full iteration ago,
            // latency hidden) and orders last iteration's slot-nxt reads
            // before this iteration's DMA overwrites it.
            __syncthreads();

            int nxt = cur ^ 1;
            if (!(last && kc == K - 1))
                stageB((kc + 1 < K) ? kc + 1 : 0, nxt);

            // x(t+1) gather issued in the kc==0 body: drained no earlier
            // than iter-1's barrier (a full iteration of head start).
            if (kc == 0 && !last) {
                int node = paths[(p0 + grow) * LPATH + t + 1];
                gv = __builtin_nontemporal_load(
                    (const float4v*)(embedding + (size_t)node * DIM + gk0));
            }

            // A fragment
            short8v a;
            if (kc < 8) {
                a = *(const short8v*)(sAx + kc * 512 + lane * 8);
            } else {
                int cg  = (kc - 8) * 4 + quad;    // 16-B group of h row
                int cgs = cg ^ (l15 & 7);         // XOR swizzle (bank-spread)
                a = *(const short8v*)(&h_lds[l15 * 256 + cgs * 8]);
            }
            // B fragments (transient: ds_read -> MFMA)
#pragma unroll
            for (int g = 0; g < 4; ++g) {
                short8v bf = *(const short8v*)(&sB[cur][g * 8192 + quad * 2048 + unit * 8]);
                acc[g] = __builtin_amdgcn_mfma_f32_16x16x32_bf16(a, bf, acc[g], 0, 0, 0);
            }
            cur = nxt;
        }

        // tail barrier: all waves' kc reads (sAx, h_lds, sB) are complete
        // before the tail overwrites sAx/h_lds.
        __syncthreads();

        // stage sAx for next step
        if (!last) {
            short4v pk = {(short)f2bf(gv[0]), (short)f2bf(gv[1]),
                          (short)f2bf(gv[2]), (short)f2bf(gv[3])};
            *(short4v*)(&sAx[gdst]) = pk;
        }

        // pointwise LSTM update: 4 cells/lane, c persistent in registers
        float hv[4];
#pragma unroll
        for (int r = 0; r < 4; ++r) {
            float iv = acc[0][r] + bb[0];
            float fv = acc[1][r] + bb[1];
            float gg = acc[2][r] + bb[2];
            float ov = acc[3][r] + bb[3];
            float cn = fast_sigmoid(fv) * cc[r] + fast_sigmoid(iv) * fast_tanh(gg);
            cc[r] = cn;
            hv[r] = fast_sigmoid(ov) * fast_tanh(cn);
        }

        // write new h into h_lds (same XOR swizzle as the read side);
        // visible to next step's kc>=8 reads via that step's iter barriers.
#pragma unroll
        for (int r = 0; r < 4; ++r) {
            int pr  = quad * 4 + r;
            int cgs = (unit >> 3) ^ (pr & 7);
            h_lds[pr * 256 + cgs * 8 + (unit & 7)] = (short)f2bf(hv[r]);
        }

        if (last) {
            // per-path max over this wave's 16 units -> LDS partials
#pragma unroll
            for (int r = 0; r < 4; ++r) {
                float m = hv[r];
                m = fmaxf(m, __shfl_xor(m, 1, 64));
                m = fmaxf(m, __shfl_xor(m, 2, 64));
                m = fmaxf(m, __shfl_xor(m, 4, 64));
                m = fmaxf(m, __shfl_xor(m, 8, 64));
                if (l15 == 0) red[(quad * 4 + r) * 16 + w] = m;
            }
        }
    }

    __syncthreads();   // epilogue: h_lds + red writes visible

    // logits: block-owned paths -> plain stores, no atomics
    if (tid < 16) {
        float m = red[tid * 16];
#pragma unroll
        for (int j = 1; j < 16; ++j) m = fmaxf(m, red[tid * 16 + j]);
        logits[p0 + tid] = m;
    }
    // h_final writeback, coalesced: de-swizzle (group i5 of row lives at
    // swizzled slot cgs = i5 ^ (row&7); store it at its TRUE offset i5*8).
    if (tid < 512) {
        int row = tid >> 5, i5 = tid & 31;
        int cgs = i5 ^ (row & 7);
        short8v v = *(const short8v*)(&h_lds[row * 256 + cgs * 8]);
        *(short8v*)(h_final + (size_t)(p0 + row) * HID + (size_t)i5 * 8) = v;
    }
}

// ---------------------------------------------------------------------------
// K2: fused softmax + attention + (last block) final linear+sigmoid.
// 256 blocks x 256 threads; each block redundantly computes the global
// softmax scalars from the 16 KB logits array, accumulates its 16 paths
// into path_emb, then the LAST block (device-scope ticket, properly
// fenced+barriered) computes out.
// ---------------------------------------------------------------------------
__global__ void attn_final_kernel(const unsigned short* __restrict__ h_final,
                                  const float* __restrict__ logits,
                                  float* __restrict__ path_emb,
                                  unsigned int* __restrict__ done,
                                  const float* __restrict__ embedding,
                                  const int* __restrict__ user_id,
                                  const int* __restrict__ item_id,
                                  const float* __restrict__ w_lin,
                                  const float* __restrict__ b_lin,
                                  float* __restrict__ out) {
    __shared__ float red[256];
    __shared__ float wts[16];
    __shared__ int lastf;
    int tid = threadIdx.x;
    int p0  = blockIdx.x * 16;

    float vals[16];
    float m = -1e30f;
#pragma unroll
    for (int i = 0; i < 16; ++i) {
        vals[i] = logits[i * 256 + tid];
        m = fmaxf(m, vals[i]);
    }
    red[tid] = m; __syncthreads();
    for (int s = 128; s > 0; s >>= 1) {
        if (tid < s) red[tid] = fmaxf(red[tid], red[tid + s]);
        __syncthreads();
    }
    m = red[0]; __syncthreads();
    float sum = 0.0f;
#pragma unroll
    for (int i = 0; i < 16; ++i) sum += __expf(vals[i] - m);
    red[tid] = sum; __syncthreads();
    for (int s = 128; s > 0; s >>= 1) {
        if (tid < s) red[tid] += red[tid + s];
        __syncthreads();
    }
    if (tid == 0) red[0] = 1.0f / red[0];
    __syncthreads();
    float invZ = red[0];
    if (tid < 16) wts[tid] = __expf(logits[p0 + tid] - m) * invZ;
    __syncthreads();

    float acc = 0.0f;
#pragma unroll
    for (int j = 0; j < 16; ++j)
        acc += wts[j] * bf2f(h_final[(size_t)(p0 + j) * HID + tid]);
    atomicAdd(&path_emb[tid], acc);

    // release: every thread's add made visible, then whole block synced,
    // THEN the ticket increments.
    __threadfence();
    __syncthreads();
    if (tid == 0) {
        unsigned int old = atomicAdd(done, 1u);
        lastf = (old == 255u) ? 1 : 0;
    }
    __syncthreads();
    if (lastf) {
        __threadfence();                 // acquire all blocks' partials
        float pe = __hip_atomic_load(&path_emb[tid], __ATOMIC_RELAXED,
                                     __HIP_MEMORY_SCOPE_AGENT);
        int u  = user_id[0];
        int it = item_id[0];
        float s = w_lin[tid]       * embedding[(size_t)u  * DIM + tid]
                + w_lin[256 + tid] * embedding[(size_t)it * DIM + tid]
                + w_lin[512 + tid] * pe;
        red[tid] = s; __syncthreads();
        for (int st = 128; st > 0; st >>= 1) {
            if (tid < st) red[tid] += red[tid + st];
            __syncthreads();
        }
        if (tid == 0) out[0] = 1.0f / (1.0f + __expf(-(red[0] + b_lin[0])));
    }
}

// ---------------------------------------------------------------------------
extern "C" void kernel_launch(void* const* d_in, const int* in_sizes, int n_in,
                              void* d_out, int out_size, void* d_ws, size_t ws_size,
                              hipStream_t stream) {
    const float* embedding = (const float*)d_in[0];
    const float* w_ih      = (const float*)d_in[1];
    const float* w_hh      = (const float*)d_in[2];
    const float* b_ih      = (const float*)d_in[3];
    const float* b_hh      = (const float*)d_in[4];
    const float* w_lin     = (const float*)d_in[5];
    const float* b_lin     = (const float*)d_in[6];
    const int*   paths     = (const int*)d_in[7];
    const int*   user_id   = (const int*)d_in[8];
    const int*   item_id   = (const int*)d_in[9];
    float* outp = (float*)d_out;

    // workspace layout (~3.1 MB), 256-B aligned
    char* ws = (char*)d_ws;
    size_t off = 0;
    auto alloc = [&](size_t n) { void* p = ws + off; off = (off + n + 255) & ~(size_t)255; return p; };
    unsigned short* WfB      = (unsigned short*)alloc((size_t)1024 * 512 * 2);   // 1 MB
    float*          bias     = (float*)alloc(1024 * 4);                          // 4 KB
    float*          path_emb = (float*)alloc(HID * 4);                           // 1 KB
    float*          logits   = (float*)alloc(NPATHS * 4);                        // 16 KB
    unsigned short* h_final  = (unsigned short*)alloc((size_t)NPATHS * HID * 2); // 2 MB
    unsigned int*   done     = (unsigned int*)alloc(4);

    prep_kernel<<<512, 256, 0, stream>>>(w_ih, w_hh, b_ih, b_hh, WfB, bias,
                                         path_emb, done);

    mega_kernel<<<256, 1024, 0, stream>>>(embedding, paths, WfB, bias,
                                          h_final, logits);

    attn_final_kernel<<<256, 256, 0, stream>>>(h_final, logits, path_emb, done,
                                               embedding, user_id, item_id,
                                               w_lin, b_lin, outp);
}

// Round 10
// 259.243 us; speedup vs baseline: 2.0423x; 1.0722x over previous
//
#include <hip/hip_runtime.h>
#include <stdint.h>

#define NPATHS 4096
#define LPATH  8
#define DIM    256
#define HID    256

typedef short  short4v __attribute__((ext_vector_type(4)));
typedef short  short8v __attribute__((ext_vector_type(8)));
typedef float  float4v __attribute__((ext_vector_type(4)));

__device__ __forceinline__ unsigned short f2bf(float f) {
    union { float f; uint32_t u; } v; v.f = f;
    uint32_t u = v.u;
    u += 0x7FFFu + ((u >> 16) & 1u);   // round-to-nearest-even
    return (unsigned short)(u >> 16);
}
__device__ __forceinline__ float bf2f(unsigned short s) {
    return __uint_as_float(((uint32_t)s) << 16);
}
__device__ __forceinline__ float fast_sigmoid(float x) {
    return 1.0f / (1.0f + __expf(-x));
}
__device__ __forceinline__ float fast_tanh(float x) {
    x = fminf(15.0f, fmaxf(-15.0f, x));
    float e = __expf(2.0f * x);
    return (e - 1.0f) / (e + 1.0f);
}

// ---------------------------------------------------------------------------
// K0: pack weights into B-fragment order + bias + zero path_emb/done.
// WfB layout (shorts): [(g*16+kc)][quad][unit][8]
//   -> per (wave,kc,gate) the 16 lanes of a quarter-wave read 256 B
//      contiguous (4 dense segments per wave load -- coalesced).
// Fragment CONTENTS per (g,kc,unit,quad,j) identical to the proven R5 kernel:
//   element k = kc*32 + quad*8 + j of row g*256+unit.
// ---------------------------------------------------------------------------
__global__ void prep_kernel(const float* __restrict__ w_ih, const float* __restrict__ w_hh,
                            const float* __restrict__ b_ih, const float* __restrict__ b_hh,
                            unsigned short* __restrict__ WfB, float* __restrict__ bias,
                            float* __restrict__ path_emb, unsigned int* __restrict__ done) {
    int gid  = blockIdx.x * 256 + threadIdx.x;    // 0..131071
    int base = gid * 4;                           // short index, %4==0
    int j0   = base & 7;                          // 0 or 4
    int unit = (base >> 3) & 255;
    int quad = (base >> 11) & 3;
    int gkc  = base >> 13;                        // g*16+kc, 0..63
    int g    = gkc >> 4, kc = gkc & 15;
    int row  = g * 256 + unit;
    int k    = kc * 32 + quad * 8 + j0;
    const float* src = (k < DIM) ? (w_ih + (size_t)row * DIM + k)
                                 : (w_hh + (size_t)row * HID + (k - DIM));
    float4 v = *(const float4*)src;
    short4v pk = {(short)f2bf(v.x), (short)f2bf(v.y), (short)f2bf(v.z), (short)f2bf(v.w)};
    *(short4v*)(WfB + base) = pk;
    if (gid < 1024) bias[gid] = b_ih[gid] + b_hh[gid];
    if (gid < 256)  path_emb[gid] = 0.0f;
    if (gid == 0)   *done = 0u;
}

// ---------------------------------------------------------------------------
// K1 (mega): ALL 8 LSTM steps in one kernel. 256 blocks x 1024 threads.
//
// SPILL LESSON (R3-R6): 1024-thread blocks get a ~64-VGPR budget; any
// persistent per-lane state beyond ~60 regs spills in-loop (R4/R6: 550/357
// MB scratch traffic). PIPELINE LESSON (R8/R9): staging B through LDS is a
// pure pass-through (zero intra-step reuse: each wave reads only its own
// unit slice, once) -- the 64 KB/iter LDS round-trip (~950-1500 cyc of LDS
// port time) + a 16-wave barrier per iter put measured iter time at ~2660
// cyc vs the 1024-cyc L2 delivery bound.
//
// R10: B goes DIRECTLY global -> VGPR, transiently (4 x global_load_dwordx4
// per wave per kc, ~16 VGPR live briefly; total demand ~56 fits 64 with no
// spill). B is per-wave-private -> the kc loop has NO barriers (120 -> 16
// for the whole kernel, 2 per step for h_lds/sAx ordering). Latency hiding
// is cross-wave: 16 waves x 4 KB = 64 KB outstanding >> ~19 KB BW-delay
// product of a ~300cyc L2 hit at ~64 B/cyc, so the CU's L2 return channel
// (the binding resource, ~1024 cyc per 64 KB kc-slice) stays saturated.
//
// Block owns 16 paths x all 256 units -> recurrence block-local:
//   h: 8 KB XOR-swizzled LDS (bf16), c: registers (4 f32/lane),
//   x: gathered inline one step ahead (nontemporal), staged into sAx at the
//      step tail. LDS total ~17 KB.
// At t=7: per-path max -> logits (block-owned), h -> h_final (de-swizzled).
// ---------------------------------------------------------------------------
__global__ __launch_bounds__(1024)
__attribute__((amdgpu_waves_per_eu(4, 4)))
void mega_kernel(const float* __restrict__ embedding, const int* __restrict__ paths,
                 const unsigned short* __restrict__ WfB, const float* __restrict__ bias,
                 unsigned short* __restrict__ h_final, float* __restrict__ logits) {
    __shared__ __align__(16) short sAx[8 * 512];      // x A-frags (8 KB)
    __shared__ __align__(16) short h_lds[16 * 256];   // h (bf16), XOR-swizzled (8 KB)
    __shared__ float red[16 * 16];                    // per-wave row-max partials

    const int tid  = threadIdx.x;
    const int w    = tid >> 6;        // 0..15
    const int lane = tid & 63;
    const int l15  = lane & 15;
    const int quad = lane >> 4;
    const int p0   = blockIdx.x * 16;
    const int unit = w * 16 + l15;    // this wave's unit-frag

    // per-lane B base (shorts): fragment for (gate g, kc) lives at
    // bb0 + (g*16+kc)*8192
    const short* bb0 = (const short*)WfB + quad * 2048 + unit * 8;

    float bb[4];
#pragma unroll
    for (int g = 0; g < 4; ++g) bb[g] = bias[g * 256 + unit];

    // gather x(0): 4 floats/thread -> one b64 LDS write (fragment order)
    const int grow = tid & 15;            // path row
    const int gk0  = (tid >> 4) * 4;      // k offset 0..252
    const int gdst = (gk0 >> 5) * 512 + (((gk0 >> 3) & 3) * 16 + grow) * 8 + (gk0 & 4);
    {
        int node = paths[(p0 + grow) * LPATH];
        float4v v = __builtin_nontemporal_load(
            (const float4v*)(embedding + (size_t)node * DIM + gk0));
        short4v pk = {(short)f2bf(v[0]), (short)f2bf(v[1]),
                      (short)f2bf(v[2]), (short)f2bf(v[3])};
        *(short4v*)(&sAx[gdst]) = pk;
    }

    float cc[4] = {0.0f, 0.0f, 0.0f, 0.0f};

    __syncthreads();                      // x(0) staged

#pragma unroll 1
    for (int t = 0; t < LPATH; ++t) {
        const bool first = (t == 0), last = (t == LPATH - 1);
        const int  K     = first ? 8 : 16;

        // issue gather of x(t+1) early (nontemporal; consumed at step tail)
        float4v gv;
        if (!last) {
            int node = paths[(p0 + grow) * LPATH + t + 1];
            gv = __builtin_nontemporal_load(
                (const float4v*)(embedding + (size_t)node * DIM + gk0));
        }

        float4v acc[4];
        const float4v z4 = {0.0f, 0.0f, 0.0f, 0.0f};
#pragma unroll
        for (int g = 0; g < 4; ++g) acc[g] = z4;

        // kc loop: NO barriers. B is per-wave-private, loaded transiently.
#pragma unroll 1
        for (int kc = 0; kc < K; ++kc) {
            // A fragment (LDS)
            short8v a;
            if (kc < 8) {
                a = *(const short8v*)(sAx + kc * 512 + lane * 8);
            } else {
                int cg  = (kc - 8) * 4 + quad;    // 16-B group of h row
                int cgs = cg ^ (l15 & 7);         // XOR swizzle (bank-spread)
                a = *(const short8v*)(&h_lds[l15 * 256 + cgs * 8]);
            }
            // B fragments: direct global->VGPR (transient), then MFMA
            const short* bk = bb0 + kc * 8192;
            short8v bf0 = *(const short8v*)(bk);
            short8v bf1 = *(const short8v*)(bk + 131072);
            short8v bf2 = *(const short8v*)(bk + 262144);
            short8v bf3 = *(const short8v*)(bk + 393216);
            acc[0] = __builtin_amdgcn_mfma_f32_16x16x32_bf16(a, bf0, acc[0], 0, 0, 0);
            acc[1] = __builtin_amdgcn_mfma_f32_16x16x32_bf16(a, bf1, acc[1], 0, 0, 0);
            acc[2] = __builtin_amdgcn_mfma_f32_16x16x32_bf16(a, bf2, acc[2], 0, 0, 0);
            acc[3] = __builtin_amdgcn_mfma_f32_16x16x32_bf16(a, bf3, acc[3], 0, 0, 0);
        }

        // all waves' sAx/h_lds reads complete before the tail overwrites them
        __syncthreads();

        // stage sAx for next step
        if (!last) {
            short4v pk = {(short)f2bf(gv[0]), (short)f2bf(gv[1]),
                          (short)f2bf(gv[2]), (short)f2bf(gv[3])};
            *(short4v*)(&sAx[gdst]) = pk;
        }

        // pointwise LSTM update: 4 cells/lane, c persistent in registers
        float hv[4];
#pragma unroll
        for (int r = 0; r < 4; ++r) {
            float iv = acc[0][r] + bb[0];
            float fv = acc[1][r] + bb[1];
            float gg = acc[2][r] + bb[2];
            float ov = acc[3][r] + bb[3];
            float cn = fast_sigmoid(fv) * cc[r] + fast_sigmoid(iv) * fast_tanh(gg);
            cc[r] = cn;
            hv[r] = fast_sigmoid(ov) * fast_tanh(cn);
        }

        // write new h into h_lds (same XOR swizzle as the read side)
#pragma unroll
        for (int r = 0; r < 4; ++r) {
            int pr  = quad * 4 + r;
            int cgs = (unit >> 3) ^ (pr & 7);
            h_lds[pr * 256 + cgs * 8 + (unit & 7)] = (short)f2bf(hv[r]);
        }

        if (last) {
            // per-path max over this wave's 16 units -> LDS partials
#pragma unroll
            for (int r = 0; r < 4; ++r) {
                float m = hv[r];
                m = fmaxf(m, __shfl_xor(m, 1, 64));
                m = fmaxf(m, __shfl_xor(m, 2, 64));
                m = fmaxf(m, __shfl_xor(m, 4, 64));
                m = fmaxf(m, __shfl_xor(m, 8, 64));
                if (l15 == 0) red[(quad * 4 + r) * 16 + w] = m;
            }
        }
        __syncthreads();   // h_lds/sAx/red writes visible for next step reads
    }

    // logits: block-owned paths -> plain stores, no atomics
    if (tid < 16) {
        float m = red[tid * 16];
#pragma unroll
        for (int j = 1; j < 16; ++j) m = fmaxf(m, red[tid * 16 + j]);
        logits[p0 + tid] = m;
    }
    // h_final writeback, coalesced: de-swizzle (group i5 of row lives at
    // swizzled slot cgs = i5 ^ (row&7); store it at its TRUE offset i5*8).
    if (tid < 512) {
        int row = tid >> 5, i5 = tid & 31;
        int cgs = i5 ^ (row & 7);
        short8v v = *(const short8v*)(&h_lds[row * 256 + cgs * 8]);
        *(short8v*)(h_final + (size_t)(p0 + row) * HID + (size_t)i5 * 8) = v;
    }
}

// ---------------------------------------------------------------------------
// K2: fused softmax + attention + (last block) final linear+sigmoid.
// 256 blocks x 256 threads; each block redundantly computes the global
// softmax scalars from the 16 KB logits array, accumulates its 16 paths
// into path_emb, then the LAST block (device-scope ticket, properly
// fenced+barriered) computes out.
// ---------------------------------------------------------------------------
__global__ void attn_final_kernel(const unsigned short* __restrict__ h_final,
                                  const float* __restrict__ logits,
                                  float* __restrict__ path_emb,
                                  unsigned int* __restrict__ done,
                                  const float* __restrict__ embedding,
                                  const int* __restrict__ user_id,
                                  const int* __restrict__ item_id,
                                  const float* __restrict__ w_lin,
                                  const float* __restrict__ b_lin,
                                  float* __restrict__ out) {
    __shared__ float red[256];
    __shared__ float wts[16];
    __shared__ int lastf;
    int tid = threadIdx.x;
    int p0  = blockIdx.x * 16;

    float vals[16];
    float m = -1e30f;
#pragma unroll
    for (int i = 0; i < 16; ++i) {
        vals[i] = logits[i * 256 + tid];
        m = fmaxf(m, vals[i]);
    }
    red[tid] = m; __syncthreads();
    for (int s = 128; s > 0; s >>= 1) {
        if (tid < s) red[tid] = fmaxf(red[tid], red[tid + s]);
        __syncthreads();
    }
    m = red[0]; __syncthreads();
    float sum = 0.0f;
#pragma unroll
    for (int i = 0; i < 16; ++i) sum += __expf(vals[i] - m);
    red[tid] = sum; __syncthreads();
    for (int s = 128; s > 0; s >>= 1) {
        if (tid < s) red[tid] += red[tid + s];
        __syncthreads();
    }
    if (tid == 0) red[0] = 1.0f / red[0];
    __syncthreads();
    float invZ = red[0];
    if (tid < 16) wts[tid] = __expf(logits[p0 + tid] - m) * invZ;
    __syncthreads();

    float acc = 0.0f;
#pragma unroll
    for (int j = 0; j < 16; ++j)
        acc += wts[j] * bf2f(h_final[(size_t)(p0 + j) * HID + tid]);
    atomicAdd(&path_emb[tid], acc);

    // release: every thread's add made visible, then whole block synced,
    // THEN the ticket increments.
    __threadfence();
    __syncthreads();
    if (tid == 0) {
        unsigned int old = atomicAdd(done, 1u);
        lastf = (old == 255u) ? 1 : 0;
    }
    __syncthreads();
    if (lastf) {
        __threadfence();                 // acquire all blocks' partials
        float pe = __hip_atomic_load(&path_emb[tid], __ATOMIC_RELAXED,
                                     __HIP_MEMORY_SCOPE_AGENT);
        int u  = user_id[0];
        int it = item_id[0];
        float s = w_lin[tid]       * embedding[(size_t)u  * DIM + tid]
                + w_lin[256 + tid] * embedding[(size_t)it * DIM + tid]
                + w_lin[512 + tid] * pe;
        red[tid] = s; __syncthreads();
        for (int st = 128; st > 0; st >>= 1) {
            if (tid < st) red[tid] += red[tid + st];
            __syncthreads();
        }
        if (tid == 0) out[0] = 1.0f / (1.0f + __expf(-(red[0] + b_lin[0])));
    }
}

// ---------------------------------------------------------------------------
extern "C" void kernel_launch(void* const* d_in, const int* in_sizes, int n_in,
                              void* d_out, int out_size, void* d_ws, size_t ws_size,
                              hipStream_t stream) {
    const float* embedding = (const float*)d_in[0];
    const float* w_ih      = (const float*)d_in[1];
    const float* w_hh      = (const float*)d_in[2];
    const float* b_ih      = (const float*)d_in[3];
    const float* b_hh      = (const float*)d_in[4];
    const float* w_lin     = (const float*)d_in[5];
    const float* b_lin     = (const float*)d_in[6];
    const int*   paths     = (const int*)d_in[7];
    const int*   user_id   = (const int*)d_in[8];
    const int*   item_id   = (const int*)d_in[9];
    float* outp = (float*)d_out;

    // workspace layout (~3.1 MB), 256-B aligned
    char* ws = (char*)d_ws;
    size_t off = 0;
    auto alloc = [&](size_t n) { void* p = ws + off; off = (off + n + 255) & ~(size_t)255; return p; };
    unsigned short* WfB      = (unsigned short*)alloc((size_t)1024 * 512 * 2);   // 1 MB
    float*          bias     = (float*)alloc(1024 * 4);                          // 4 KB
    float*          path_emb = (float*)alloc(HID * 4);                           // 1 KB
    float*          logits   = (float*)alloc(NPATHS * 4);                        // 16 KB
    unsigned short* h_final  = (unsigned short*)alloc((size_t)NPATHS * HID * 2); // 2 MB
    unsigned int*   done     = (unsigned int*)alloc(4);

    prep_kernel<<<512, 256, 0, stream>>>(w_ih, w_hh, b_ih, b_hh, WfB, bias,
                                         path_emb, done);

    mega_kernel<<<256, 1024, 0, stream>>>(embedding, paths, WfB, bias,
                                          h_final, logits);

    attn_final_kernel<<<256, 256, 0, stream>>>(h_final, logits, path_emb, done,
                                               embedding, user_id, item_id,
                                               w_lin, b_lin, outp);
}

// Round 12
// 256.971 us; speedup vs baseline: 2.0604x; 1.0088x over previous
//
#include <hip/hip_runtime.h>
#include <stdint.h>

#define NPATHS 4096
#define LPATH  8
#define DIM    256
#define HID    256

typedef short  short4v __attribute__((ext_vector_type(4)));
typedef short  short8v __attribute__((ext_vector_type(8)));
typedef float  float4v __attribute__((ext_vector_type(4)));

__device__ __forceinline__ unsigned short f2bf(float f) {
    union { float f; uint32_t u; } v; v.f = f;
    uint32_t u = v.u;
    u += 0x7FFFu + ((u >> 16) & 1u);   // round-to-nearest-even
    return (unsigned short)(u >> 16);
}
__device__ __forceinline__ float bf2f(unsigned short s) {
    return __uint_as_float(((uint32_t)s) << 16);
}
__device__ __forceinline__ float fast_sigmoid(float x) {
    return 1.0f / (1.0f + __expf(-x));
}
__device__ __forceinline__ float fast_tanh(float x) {
    x = fminf(15.0f, fmaxf(-15.0f, x));
    float e = __expf(2.0f * x);
    return (e - 1.0f) / (e + 1.0f);
}

// ---------------------------------------------------------------------------
// K0: pack weights into B-fragment order + bias + zero path_emb/done.
// WfB layout (shorts): [(g*16+kc)][quad][unit][8]
//   -> per (wave,kc,gate) the 16 lanes of a quarter-wave read 256 B
//      contiguous (4 dense segments per wave load -- coalesced).
// Fragment CONTENTS per (g,kc,unit,quad,j) identical to the proven R5 kernel:
//   element k = kc*32 + quad*8 + j of row g*256+unit.
// ---------------------------------------------------------------------------
__global__ void prep_kernel(const float* __restrict__ w_ih, const float* __restrict__ w_hh,
                            const float* __restrict__ b_ih, const float* __restrict__ b_hh,
                            unsigned short* __restrict__ WfB, float* __restrict__ bias,
                            float* __restrict__ path_emb, unsigned int* __restrict__ done) {
    int gid  = blockIdx.x * 256 + threadIdx.x;    // 0..131071
    int base = gid * 4;                           // short index, %4==0
    int j0   = base & 7;                          // 0 or 4
    int unit = (base >> 3) & 255;
    int quad = (base >> 11) & 3;
    int gkc  = base >> 13;                        // g*16+kc, 0..63
    int g    = gkc >> 4, kc = gkc & 15;
    int row  = g * 256 + unit;
    int k    = kc * 32 + quad * 8 + j0;
    const float* src = (k < DIM) ? (w_ih + (size_t)row * DIM + k)
                                 : (w_hh + (size_t)row * HID + (k - DIM));
    float4 v = *(const float4*)src;
    short4v pk = {(short)f2bf(v.x), (short)f2bf(v.y), (short)f2bf(v.z), (short)f2bf(v.w)};
    *(short4v*)(WfB + base) = pk;
    if (gid < 1024) bias[gid] = b_ih[gid] + b_hh[gid];
    if (gid < 256)  path_emb[gid] = 0.0f;
    if (gid == 0)   *done = 0u;
}

// ---------------------------------------------------------------------------
// K1 (mega): ALL 8 LSTM steps in one kernel. 256 blocks x 1024 threads.
//
// SPILL LESSON (R3-R6): 1024-thread blocks get a ~64-VGPR budget; keep
// per-lane demand <= ~60. LDS LESSON (R8/R9): B staging through LDS is a
// pure pass-through -- stream B global->VGPR directly.
//
// LATENCY LESSON (R10 -> R11): R10's unpipelined kc loop measured ~2270
// cyc/iter vs the ~1150-cyc L2 service bound (64 KB/iter/CU @ ~56 B/cyc):
// each wave issued loads, stalled the full burst-queueing latency, THEN
// issued the next loads. R11 pipelines with ZERO extra registers via
// consume-then-reload: acc_g = mfma(pa, pf_g, acc_g); pf_g = load(kc_next)
// -- old pf dies at MFMA issue, same register re-targeted, every load gets
// a full iteration (~1150 cyc) of lead; compiler emits counted vmcnt for
// this (no barriers / DMA in the loop, so it is not defeated). B prefetch
// carries across step boundaries (B is t-invariant); A (LDS) prefetch is
// within-step only (next step's sAx/h_lds not yet written; the stale pa
// loaded at the last iteration is discarded -- step-top reloads pa after
// the barrier).
//
// Plus per-block kc ROTATION (kc = half + ((i + blk&7)&7)): all 32 CUs on
// an XCD otherwise request the SAME 64 KB slice simultaneously every iter
// (L2 line/bank camping). Rotation spreads simultaneous requests across 16
// distinct slices. Accumulation order changes -> fp-rounding-level only.
//
// Block owns 16 paths x all 256 units -> recurrence block-local:
//   h: 8 KB XOR-swizzled LDS (bf16), c: registers (4 f32/lane),
//   x: gathered inline one step ahead (nontemporal). LDS total ~17 KB.
// At t=7: per-path max -> logits (block-owned), h -> h_final (de-swizzled).
//
// (R11 bench died on container infra; audit found no hang/correctness risk
//  -- all barriers uniform, no DMA, no spins. Resubmitted unchanged, same
//  as the R7->R8 flake.)
// ---------------------------------------------------------------------------
__global__ __launch_bounds__(1024)
__attribute__((amdgpu_waves_per_eu(4, 4)))
void mega_kernel(const float* __restrict__ embedding, const int* __restrict__ paths,
                 const unsigned short* __restrict__ WfB, const float* __restrict__ bias,
                 unsigned short* __restrict__ h_final, float* __restrict__ logits) {
    __shared__ __align__(16) short sAx[8 * 512];      // x A-frags (8 KB)
    __shared__ __align__(16) short h_lds[16 * 256];   // h (bf16), XOR-swizzled (8 KB)
    __shared__ float red[16 * 16];                    // per-wave row-max partials

    const int tid  = threadIdx.x;
    const int w    = tid >> 6;        // 0..15
    const int lane = tid & 63;
    const int l15  = lane & 15;
    const int quad = lane >> 4;
    const int p0   = blockIdx.x * 16;
    const int unit = w * 16 + l15;    // this wave's unit-frag
    const int roff = blockIdx.x & 7;  // kc rotation (L2 decorrelation)

    // per-lane B base (shorts): fragment for (gate g, kc) lives at
    // bb0 + (g*16+kc)*8192
    const short* bb0 = (const short*)WfB + quad * 2048 + unit * 8;

    float bb[4];
#pragma unroll
    for (int g = 0; g < 4; ++g) bb[g] = bias[g * 256 + unit];

    // gather x(0): 4 floats/thread -> one b64 LDS write (fragment order)
    const int grow = tid & 15;            // path row
    const int gk0  = (tid >> 4) * 4;      // k offset 0..252
    const int gdst = (gk0 >> 5) * 512 + (((gk0 >> 3) & 3) * 16 + grow) * 8 + (gk0 & 4);
    {
        int node = paths[(p0 + grow) * LPATH];
        float4v v = __builtin_nontemporal_load(
            (const float4v*)(embedding + (size_t)node * DIM + gk0));
        short4v pk = {(short)f2bf(v[0]), (short)f2bf(v[1]),
                      (short)f2bf(v[2]), (short)f2bf(v[3])};
        *(short4v*)(&sAx[gdst]) = pk;
    }

    float cc[4] = {0.0f, 0.0f, 0.0f, 0.0f};

    __syncthreads();                      // x(0) staged

    // B prefetch prologue: first iteration of every step uses kc = roff
    short8v pf0, pf1, pf2, pf3;
    {
        const short* bk = bb0 + roff * 8192;
        pf0 = *(const short8v*)(bk);
        pf1 = *(const short8v*)(bk + 131072);
        pf2 = *(const short8v*)(bk + 262144);
        pf3 = *(const short8v*)(bk + 393216);
    }

#pragma unroll 1
    for (int t = 0; t < LPATH; ++t) {
        const bool last = (t == LPATH - 1);
        const int  K    = (t == 0) ? 8 : 16;

        // issue gather of x(t+1) early (nontemporal; consumed at step tail)
        float4v gv;
        if (!last) {
            int node = paths[(p0 + grow) * LPATH + t + 1];
            gv = __builtin_nontemporal_load(
                (const float4v*)(embedding + (size_t)node * DIM + gk0));
        }

        float4v acc[4];
        const float4v z4 = {0.0f, 0.0f, 0.0f, 0.0f};
#pragma unroll
        for (int g = 0; g < 4; ++g) acc[g] = z4;

        // A prefetch for i=0 (kc = roff, x-half; sAx ready since last barrier)
        short8v pa = *(const short8v*)(sAx + roff * 512 + lane * 8);

        // kc loop: NO barriers; 1-iteration software pipeline on pa/pf.
#pragma unroll 1
        for (int i = 0; i < K; ++i) {
            int ip  = i + 1;
            // next kc in the flat schedule (next step starts at kc = roff;
            // dummy at the very end -- value overwritten at next step top)
            int kcn = (ip < K) ? ((ip < 8) ? ((ip + roff) & 7)
                                           : (8 + ((ip + roff) & 7)))
                               : roff;
            const short* bk = bb0 + kcn * 8192;

            // consume prefetched fragments; immediately re-issue same regs
            acc[0] = __builtin_amdgcn_mfma_f32_16x16x32_bf16(pa, pf0, acc[0], 0, 0, 0);
            pf0 = *(const short8v*)(bk);
            acc[1] = __builtin_amdgcn_mfma_f32_16x16x32_bf16(pa, pf1, acc[1], 0, 0, 0);
            pf1 = *(const short8v*)(bk + 131072);
            acc[2] = __builtin_amdgcn_mfma_f32_16x16x32_bf16(pa, pf2, acc[2], 0, 0, 0);
            pf2 = *(const short8v*)(bk + 262144);
            acc[3] = __builtin_amdgcn_mfma_f32_16x16x32_bf16(pa, pf3, acc[3], 0, 0, 0);
            pf3 = *(const short8v*)(bk + 393216);

            // A for next iteration (LDS; within-step only)
            if (kcn < 8) {
                pa = *(const short8v*)(sAx + kcn * 512 + lane * 8);
            } else {
                int cg  = (kcn - 8) * 4 + quad;   // 16-B group of h row
                int cgs = cg ^ (l15 & 7);         // XOR swizzle (bank-spread)
                pa = *(const short8v*)(&h_lds[l15 * 256 + cgs * 8]);
            }
        }

        // all waves' sAx/h_lds reads complete before the tail overwrites them
        __syncthreads();

        // stage sAx for next step
        if (!last) {
            short4v pk = {(short)f2bf(gv[0]), (short)f2bf(gv[1]),
                          (short)f2bf(gv[2]), (short)f2bf(gv[3])};
            *(short4v*)(&sAx[gdst]) = pk;
        }

        // pointwise LSTM update: 4 cells/lane, c persistent in registers
        float hv[4];
#pragma unroll
        for (int r = 0; r < 4; ++r) {
            float iv = acc[0][r] + bb[0];
            float fv = acc[1][r] + bb[1];
            float gg = acc[2][r] + bb[2];
            float ov = acc[3][r] + bb[3];
            float cn = fast_sigmoid(fv) * cc[r] + fast_sigmoid(iv) * fast_tanh(gg);
            cc[r] = cn;
            hv[r] = fast_sigmoid(ov) * fast_tanh(cn);
        }

        // write new h into h_lds (same XOR swizzle as the read side)
#pragma unroll
        for (int r = 0; r < 4; ++r) {
            int pr  = quad * 4 + r;
            int cgs = (unit >> 3) ^ (pr & 7);
            h_lds[pr * 256 + cgs * 8 + (unit & 7)] = (short)f2bf(hv[r]);
        }

        if (last) {
            // per-path max over this wave's 16 units -> LDS partials
#pragma unroll
            for (int r = 0; r < 4; ++r) {
                float m = hv[r];
                m = fmaxf(m, __shfl_xor(m, 1, 64));
                m = fmaxf(m, __shfl_xor(m, 2, 64));
                m = fmaxf(m, __shfl_xor(m, 4, 64));
                m = fmaxf(m, __shfl_xor(m, 8, 64));
                if (l15 == 0) red[(quad * 4 + r) * 16 + w] = m;
            }
        }
        __syncthreads();   // h_lds/sAx/red writes visible for next step reads
    }

    // logits: block-owned paths -> plain stores, no atomics
    if (tid < 16) {
        float m = red[tid * 16];
#pragma unroll
        for (int j = 1; j < 16; ++j) m = fmaxf(m, red[tid * 16 + j]);
        logits[p0 + tid] = m;
    }
    // h_final writeback, coalesced: de-swizzle (group i5 of row lives at
    // swizzled slot cgs = i5 ^ (row&7); store it at its TRUE offset i5*8).
    if (tid < 512) {
        int row = tid >> 5, i5 = tid & 31;
        int cgs = i5 ^ (row & 7);
        short8v v = *(const short8v*)(&h_lds[row * 256 + cgs * 8]);
        *(short8v*)(h_final + (size_t)(p0 + row) * HID + (size_t)i5 * 8) = v;
    }
}

// ---------------------------------------------------------------------------
// K2: fused softmax + attention + (last block) final linear+sigmoid.
// 256 blocks x 256 threads; each block redundantly computes the global
// softmax scalars from the 16 KB logits array, accumulates its 16 paths
// into path_emb, then the LAST block (device-scope ticket, properly
// fenced+barriered) computes out.
// ---------------------------------------------------------------------------
__global__ void attn_final_kernel(const unsigned short* __restrict__ h_final,
                                  const float* __restrict__ logits,
                                  float* __restrict__ path_emb,
                                  unsigned int* __restrict__ done,
                                  const float* __restrict__ embedding,
                                  const int* __restrict__ user_id,
                                  const int* __restrict__ item_id,
                                  const float* __restrict__ w_lin,
                                  const float* __restrict__ b_lin,
                                  float* __restrict__ out) {
    __shared__ float red[256];
    __shared__ float wts[16];
    __shared__ int lastf;
    int tid = threadIdx.x;
    int p0  = blockIdx.x * 16;

    float vals[16];
    float m = -1e30f;
#pragma unroll
    for (int i = 0; i < 16; ++i) {
        vals[i] = logits[i * 256 + tid];
        m = fmaxf(m, vals[i]);
    }
    red[tid] = m; __syncthreads();
    for (int s = 128; s > 0; s >>= 1) {
        if (tid < s) red[tid] = fmaxf(red[tid], red[tid + s]);
        __syncthreads();
    }
    m = red[0]; __syncthreads();
    float sum = 0.0f;
#pragma unroll
    for (int i = 0; i < 16; ++i) sum += __expf(vals[i] - m);
    red[tid] = sum; __syncthreads();
    for (int s = 128; s > 0; s >>= 1) {
        if (tid < s) red[tid] += red[tid + s];
        __syncthreads();
    }
    if (tid == 0) red[0] = 1.0f / red[0];
    __syncthreads();
    float invZ = red[0];
    if (tid < 16) wts[tid] = __expf(logits[p0 + tid] - m) * invZ;
    __syncthreads();

    float acc = 0.0f;
#pragma unroll
    for (int j = 0; j < 16; ++j)
        acc += wts[j] * bf2f(h_final[(size_t)(p0 + j) * HID + tid]);
    atomicAdd(&path_emb[tid], acc);

    // release: every thread's add made visible, then whole block synced,
    // THEN the ticket increments.
    __threadfence();
    __syncthreads();
    if (tid == 0) {
        unsigned int old = atomicAdd(done, 1u);
        lastf = (old == 255u) ? 1 : 0;
    }
    __syncthreads();
    if (lastf) {
        __threadfence();                 // acquire all blocks' partials
        float pe = __hip_atomic_load(&path_emb[tid], __ATOMIC_RELAXED,
                                     __HIP_MEMORY_SCOPE_AGENT);
        int u  = user_id[0];
        int it = item_id[0];
        float s = w_lin[tid]       * embedding[(size_t)u  * DIM + tid]
                + w_lin[256 + tid] * embedding[(size_t)it * DIM + tid]
                + w_lin[512 + tid] * pe;
        red[tid] = s; __syncthreads();
        for (int st = 128; st > 0; st >>= 1) {
            if (tid < st) red[tid] += red[tid + st];
            __syncthreads();
        }
        if (tid == 0) out[0] = 1.0f / (1.0f + __expf(-(red[0] + b_lin[0])));
    }
}

// ---------------------------------------------------------------------------
extern "C" void kernel_launch(void* const* d_in, const int* in_sizes, int n_in,
                              void* d_out, int out_size, void* d_ws, size_t ws_size,
                              hipStream_t stream) {
    const float* embedding = (const float*)d_in[0];
    const float* w_ih      = (const float*)d_in[1];
    const float* w_hh      = (const float*)d_in[2];
    const float* b_ih      = (const float*)d_in[3];
    const float* b_hh      = (const float*)d_in[4];
    const float* w_lin     = (const float*)d_in[5];
    const float* b_lin     = (const float*)d_in[6];
    const int*   paths     = (const int*)d_in[7];
    const int*   user_id   = (const int*)d_in[8];
    const int*   item_id   = (const int*)d_in[9];
    float* outp = (float*)d_out;

    // workspace layout (~3.1 MB), 256-B aligned
    char* ws = (char*)d_ws;
    size_t off = 0;
    auto alloc = [&](size_t n) { void* p = ws + off; off = (off + n + 255) & ~(size_t)255; return p; };
    unsigned short* WfB      = (unsigned short*)alloc((size_t)1024 * 512 * 2);   // 1 MB
    float*          bias     = (float*)alloc(1024 * 4);                          // 4 KB
    float*          path_emb = (float*)alloc(HID * 4);                           // 1 KB
    float*          logits   = (float*)alloc(NPATHS * 4);                        // 16 KB
    unsigned short* h_final  = (unsigned short*)alloc((size_t)NPATHS * HID * 2); // 2 MB
    unsigned int*   done     = (unsigned int*)alloc(4);

    prep_kernel<<<512, 256, 0, stream>>>(w_ih, w_hh, b_ih, b_hh, WfB, bias,
                                         path_emb, done);

    mega_kernel<<<256, 1024, 0, stream>>>(embedding, paths, WfB, bias,
                                          h_final, logits);

    attn_final_kernel<<<256, 256, 0, stream>>>(h_final, logits, path_emb, done,
                                               embedding, user_id, item_id,
                                               w_lin, b_lin, outp);
}